// Round 4
// baseline (26378.397 us; speedup 1.0000x reference)
//
#include <hip/hip_runtime.h>
#include <hip/hip_bf16.h>
#include <cstdint>

#define B_ 32
#define L_ 196
#define D_ 512
#define H_ 512
#define E_ 256
#define T_ 128
#define V_ 512
#define GRID_ 256

using u16 = unsigned short;

__device__ __forceinline__ float bf2f(u16 u) { return __uint_as_float(((unsigned)u) << 16); }
__device__ __forceinline__ u16 f2bf(float f) {
    unsigned u = __float_as_uint(f);
    return (u16)((u + 0x7FFFu + ((u >> 16) & 1u)) >> 16);
}
__device__ __forceinline__ float2 bfp(unsigned u) {
    return make_float2(__uint_as_float(u << 16), __uint_as_float(u & 0xffff0000u));
}
__device__ __forceinline__ float sigm(float x) { return 1.f / (1.f + __expf(-x)); }

// ---------------- dtype detect (bf16 vs fp32 inputs) + barrier reset ----------------
__global__ void detect_kernel(const u16* __restrict__ w, int* __restrict__ flg,
                              int* __restrict__ bar) {
    if (threadIdx.x == 0) {
        int cnt = 0;
        for (int i = 0; i < 64; ++i) {
            int e = (w[i] >> 7) & 0xFF;
            cnt += (e >= 100 && e <= 130);
        }
        flg[0] = (cnt >= 56) ? 1 : 0;
        bar[0] = 0;
    }
}

// ---------------- convert all float tensors to internal bf16 ----------------
struct ConvPtrs { const void* p[19]; };

__global__ __launch_bounds__(256) void conv_kernel(ConvPtrs cp, const int* __restrict__ flg,
                                                   u16* __restrict__ dst) {
    constexpr int NT = 19;
    constexpr unsigned off[NT + 1] = {
        0u, 3211264u, 3227648u, 3244032u, 3506176u, 3506432u, 3539200u, 3539328u,
        3539456u, 5112320u, 6160896u, 6162944u, 6164992u, 6296064u, 6754304u,
        6754664u, 6882832u, 6883192u, 7066488u, 7067000u};
    constexpr unsigned realN[NT] = {
        3211264u, 16384u, 16384u, 262144u, 256u, 32768u, 128u, 128u,
        1572864u, 1048576u, 2048u, 2048u, 131072u, 458240u, 358u,
        128164u, 358u, 183296u, 512u};
    unsigned pos = (blockIdx.x * 256u + threadIdx.x) * 4u;
    if (pos >= off[NT]) return;
    int t = 0;
#pragma unroll
    for (int i = 1; i < NT; ++i) t += (pos >= off[i]);
    unsigned local = pos - off[t];
    int bf = flg[0];
    const void* src = cp.p[t];
    u16* d = dst + off[t];
#pragma unroll
    for (int j = 0; j < 4; ++j) {
        unsigned l = local + j;
        u16 v = 0;
        if (l < realN[t]) v = bf ? ((const u16*)src)[l] : f2bf(((const float*)src)[l]);
        d[l] = v;
    }
}

// ---------------- weight transposes: wT[col][k], w1hT[col][k] ----------------
__global__ __launch_bounds__(256) void prep_kernel(const u16* __restrict__ w_ih,
                                                   const u16* __restrict__ w_hh,
                                                   const u16* __restrict__ att_w1,
                                                   u16* __restrict__ wT,
                                                   u16* __restrict__ w1hT) {
    int c = blockIdx.x, t = threadIdx.x;
    if (c < 2048) {
#pragma unroll
        for (int i = 0; i < 5; ++i) {
            int k = i * 256 + t;
            u16 v = (k < 768) ? w_ih[(size_t)k * 2048 + c] : w_hh[(size_t)(k - 768) * 2048 + c];
            wT[(size_t)c * 1280 + k] = v;
        }
    } else {
        int c2 = c - 2048;
#pragma unroll
        for (int i = 0; i < 2; ++i) {
            int k = i * 256 + t;
            w1hT[(size_t)c2 * 512 + k] = att_w1[(size_t)(512 + k) * 256 + c2];
        }
    }
}

// ---------------- embedding (shifted y) -> hze e-part ----------------
__global__ __launch_bounds__(256) void embed_kernel(const int* __restrict__ y,
                                                    const u16* __restrict__ emb,
                                                    u16* __restrict__ hze) {
    int t = threadIdx.x;
    int row0 = blockIdx.x * 4;
    for (int i = 0; i < 4; ++i) {
        int row = row0 + i;
        int b = row >> 7, tt = row & 127;
        int yin = tt ? y[b * T_ + tt - 1] : 0;
        hze[(size_t)row * 1280 + 1024 + t] = emb[yin * E_ + t];
    }
}

// ---------------- generic tiled GEMM: C = act(A @ Bw + bias) ----------------
template <bool TANH, int OMODE>
__global__ __launch_bounds__(256) void gemm_kernel(const u16* __restrict__ A, int lda,
                                                   const u16* __restrict__ Bw, int ldb,
                                                   const u16* __restrict__ bias,
                                                   void* __restrict__ Cv, int ldc,
                                                   int M, int N, int K,
                                                   const int* __restrict__ flg) {
    __shared__ float As[16][132];
    __shared__ float Bs[16][68];
    int t = threadIdx.x;
    int n0 = blockIdx.x * 64;
    int m0 = blockIdx.y * 128;
    int tx = t & 15, ty = t >> 4;
    float acc[8][4];
#pragma unroll
    for (int i = 0; i < 8; ++i)
#pragma unroll
        for (int j = 0; j < 4; ++j) acc[i][j] = 0.f;

    int ar = t >> 1, akb = (t & 1) * 8;
    int bn = t & 63, bkg = t >> 6;

    for (int k0 = 0; k0 < K; k0 += 16) {
        const u16* Ap = A + (size_t)(m0 + ar) * lda + k0 + akb;
        if (k0 + 16 <= K) {
#pragma unroll
            for (int i = 0; i < 8; ++i) As[akb + i][ar] = bf2f(Ap[i]);
        } else {
#pragma unroll
            for (int i = 0; i < 8; ++i) As[akb + i][ar] = (k0 + akb + i < K) ? bf2f(Ap[i]) : 0.f;
        }
#pragma unroll
        for (int i = 0; i < 4; ++i) {
            int kk = bkg * 4 + i;
            int kg = k0 + kk, ng = n0 + bn;
            Bs[kk][bn] = (kg < K && ng < N) ? bf2f(Bw[(size_t)kg * ldb + ng]) : 0.f;
        }
        __syncthreads();
#pragma unroll
        for (int kk = 0; kk < 16; ++kk) {
            float4 aA = *(const float4*)&As[kk][ty * 8];
            float4 aB = *(const float4*)&As[kk][ty * 8 + 4];
            float4 bv = *(const float4*)&Bs[kk][tx * 4];
            float av[8] = {aA.x, aA.y, aA.z, aA.w, aB.x, aB.y, aB.z, aB.w};
            float bb[4] = {bv.x, bv.y, bv.z, bv.w};
#pragma unroll
            for (int i = 0; i < 8; ++i)
#pragma unroll
                for (int j = 0; j < 4; ++j) acc[i][j] += av[i] * bb[j];
        }
        __syncthreads();
    }
    int obf = (OMODE == 2) ? flg[0] : 1;
    float bb[4];
#pragma unroll
    for (int j = 0; j < 4; ++j) {
        int n = n0 + tx * 4 + j;
        bb[j] = (n < N) ? bf2f(bias[n]) : 0.f;
    }
#pragma unroll
    for (int i = 0; i < 8; ++i) {
        int m = m0 + ty * 8 + i;
#pragma unroll
        for (int j = 0; j < 4; ++j) {
            int n = n0 + tx * 4 + j;
            if (n < N) {
                float v = acc[i][j] + bb[j];
                if (TANH) v = tanhf(v);
                if (OMODE == 1 || obf)
                    ((u16*)Cv)[(size_t)m * ldc + n] = f2bf(v);
                else
                    ((float*)Cv)[(size_t)m * ldc + n] = v;
            }
        }
    }
}

// ---------------- persistent decoder: whole T-loop, 3 grid barriers/step ----------------
struct DecArgs {
    const u16 *h0, *c0, *pre1, *att_w2, *att_b2, *att_w3, *w1hT, *wT, *bih, *bhh, *a;
    u16* hze;
    float *z_buf, *s_buf, *h_buf, *c_buf;
    int* bar;
};

struct SA { float x1s[28][262]; float part[28][36]; };
struct SB { float red[256]; float alpha[200]; };
struct SC { float inp[32][132]; float accs[32][9]; };
union SU { SA a; SB b; SC c; float hs[512]; };

// all-thread fences: plain stores (s_buf/z_buf/h_buf) must be agent-visible
// across XCDs; round-3 version fenced only in thread 0 (insufficient).
__device__ __forceinline__ void gridbar(int* bar, int target) {
    __threadfence();
    __syncthreads();
    if (threadIdx.x == 0) {
        __hip_atomic_fetch_add(bar, 1, __ATOMIC_ACQ_REL, __HIP_MEMORY_SCOPE_AGENT);
        while (__hip_atomic_load(bar, __ATOMIC_ACQUIRE, __HIP_MEMORY_SCOPE_AGENT) < target)
            __builtin_amdgcn_s_sleep(8);
    }
    __syncthreads();
    __threadfence();
}

__global__ __launch_bounds__(256) void decoder_kernel(DecArgs g) {
    int blk = blockIdx.x, t = threadIdx.x;
    __shared__ SU su;
    __shared__ u16 wlds[8][1288];
    __shared__ float w3s[128], b2s[128];
    int phase = 0;

    // --- one-time: stage C weight slice (8 gate-cols for d0,d0+1) into LDS ---
    int d0 = blk * 2;
#pragma unroll
    for (int i = 0; i < 5; ++i) {
        int v = i * 256 + t;           // 1280 vec8 total
        int cidx = v / 160, k8 = v % 160;
        int col = (cidx >> 1) * 512 + d0 + (cidx & 1);
        *(uint4*)&wlds[cidx][k8 * 8] = *(const uint4*)(g.wT + (size_t)col * 1280 + k8 * 8);
    }
    if (t < 128) {
        w3s[t] = bf2f(g.att_w3[t]);
        b2s[t] = bf2f(g.att_b2[t]);
    }
    float bsum[4];
    {
        int bj = t & 1;
#pragma unroll
        for (int q = 0; q < 4; ++q) {
            int col = q * 512 + d0 + bj;
            bsum[q] = bf2f(g.bih[col]) + bf2f(g.bhh[col]);
        }
    }
    if (blk < 32) {
        for (int i = t; i < 512; i += 256) {
            g.h_buf[blk * 512 + i] = bf2f(g.h0[blk * 512 + i]);
            g.c_buf[blk * 512 + i] = bf2f(g.c0[blk * 512 + i]);
        }
    }
    gridbar(g.bar, (++phase) * GRID_);

    int ab = blk >> 3, ach = blk & 7;
    int anrows = (ach == 7) ? 21 : 25;
    int arow0 = ab * 196 + ach * 25;

    for (int step = 0; step < T_; ++step) {
        int par = step & 1;
        const float* hcur = g.h_buf + par * B_ * H_;
        // ================= stage A: hterm + attention MLP scores =================
        su.hs[t] = hcur[ab * 512 + t];
        su.hs[256 + t] = hcur[ab * 512 + 256 + t];
        __syncthreads();
        float htv;
        {
            float acc = 0.f;
            const u16* wp = g.w1hT + (size_t)t * 512;
#pragma unroll 4
            for (int k = 0; k < 512; k += 8) {
                uint4 wv = *(const uint4*)(wp + k);
                float4 hA = *(const float4*)&su.hs[k];
                float4 hB = *(const float4*)&su.hs[k + 4];
                float2 w01 = bfp(wv.x), w23 = bfp(wv.y), w45 = bfp(wv.z), w67 = bfp(wv.w);
                acc += hA.x * w01.x + hA.y * w01.y + hA.z * w23.x + hA.w * w23.y +
                       hB.x * w45.x + hB.y * w45.y + hB.z * w67.x + hB.w * w67.y;
            }
            htv = acc;
        }
        __syncthreads();  // hs dead; reuse region as x1s
        for (int r = 0; r < 28; ++r) {
            float v = 0.f;
            if (r < anrows) v = tanhf(bf2f(g.pre1[(size_t)(arow0 + r) * 256 + t]) + htv);
            su.a.x1s[r][t] = v;
        }
        __syncthreads();
        if (t < 224) {
            int r0 = (t >> 5) * 4, c0v = (t & 31) * 4;
            float acc[4][4];
#pragma unroll
            for (int i = 0; i < 4; ++i)
#pragma unroll
                for (int j = 0; j < 4; ++j) acc[i][j] = 0.f;
            for (int k = 0; k < 256; k += 2) {
                float av[4][2];
#pragma unroll
                for (int i = 0; i < 4; ++i) {
                    float2 v = *(const float2*)&su.a.x1s[r0 + i][k];
                    av[i][0] = v.x;
                    av[i][1] = v.y;
                }
#pragma unroll
                for (int u = 0; u < 2; ++u) {
                    const u16* wp2 = g.att_w2 + (size_t)(k + u) * 128 + c0v;
#pragma unroll
                    for (int j = 0; j < 4; ++j) {
                        float w = bf2f(wp2[j]);
#pragma unroll
                        for (int i = 0; i < 4; ++i) acc[i][j] += av[i][u] * w;
                    }
                }
            }
#pragma unroll
            for (int i = 0; i < 4; ++i) {
                float p = 0.f;
#pragma unroll
                for (int j = 0; j < 4; ++j)
                    p += tanhf(acc[i][j] + b2s[c0v + j]) * w3s[c0v + j];
                su.a.part[r0 + i][t & 31] = p;
            }
        }
        __syncthreads();
        if (t < anrows) {
            float s = 0.f;
#pragma unroll
            for (int cg = 0; cg < 32; ++cg) s += su.a.part[t][cg];
            g.s_buf[arow0 + t] = s;  // att_b3 omitted: softmax-invariant
        }
        gridbar(g.bar, (++phase) * GRID_);
        // ================= stage B: softmax + context z =================
        if (blk < 64) {
            int b = blk >> 1, half = blk & 1;
            float v = (t < L_) ? g.s_buf[b * L_ + t] : -1e30f;
            su.b.red[t] = v;
            __syncthreads();
            for (int off = 128; off > 0; off >>= 1) {
                if (t < off) su.b.red[t] = fmaxf(su.b.red[t], su.b.red[t + off]);
                __syncthreads();
            }
            float mx = su.b.red[0];
            __syncthreads();
            float e = (t < L_) ? __expf(v - mx) : 0.f;
            su.b.red[t] = e;
            __syncthreads();
            for (int off = 128; off > 0; off >>= 1) {
                if (t < off) su.b.red[t] += su.b.red[t + off];
                __syncthreads();
            }
            float inv = 1.f / su.b.red[0];
            __syncthreads();
            if (t < L_) su.b.alpha[t] = e * inv;
            __syncthreads();
            int d = half * 256 + t;
            const u16* ap = g.a + (size_t)b * L_ * 512 + d;
            float z = 0.f;
            for (int l = 0; l < L_; ++l) z += su.b.alpha[l] * bf2f(ap[(size_t)l * 512]);
            g.z_buf[b * 512 + d] = z;
            g.hze[(size_t)(b * T_ + step) * 1280 + 512 + d] = f2bf(z);
        }
        gridbar(g.bar, (++phase) * GRID_);
        // ================= stage C: LSTM gates + state update =================
        {
            int cb = t >> 3, cc = t & 7;
            float acc = 0.f;
            for (int ck = 0; ck < 10; ++ck) {
                __syncthreads();
#pragma unroll
                for (int i = 0; i < 4; ++i) {
                    int v = i * 256 + t;       // 1024 vec4 = 32b x 128k
                    int bb = v >> 5;
                    int kk = (v & 31) * 4;
                    float4 val;
                    if (ck < 4) {
                        val = *(const float4*)(g.z_buf + bb * 512 + ck * 128 + kk);
                    } else if (ck < 6) {
                        const u16* ep = g.hze + (size_t)(bb * T_ + step) * 1280 + 1024 +
                                        (ck - 4) * 128 + kk;
                        val.x = bf2f(ep[0]); val.y = bf2f(ep[1]);
                        val.z = bf2f(ep[2]); val.w = bf2f(ep[3]);
                    } else {
                        val = *(const float4*)(g.h_buf + par * B_ * H_ + bb * 512 +
                                               (ck - 6) * 128 + kk);
                    }
                    *(float4*)&su.c.inp[bb][kk] = val;
                }
                __syncthreads();
                const u16* wrow = &wlds[cc][ck * 128];
                const float* irow = &su.c.inp[cb][0];
#pragma unroll 8
                for (int kk = 0; kk < 128; kk += 4) {
                    float4 iv = *(const float4*)(irow + kk);
                    uint2 wv = *(const uint2*)(wrow + kk);
                    float2 w01 = bfp(wv.x), w23 = bfp(wv.y);
                    acc += iv.x * w01.x + iv.y * w01.y + iv.z * w23.x + iv.w * w23.y;
                }
            }
            __syncthreads();
            su.c.accs[cb][cc] = acc;
            __syncthreads();
            if (t < 64) {
                int bb = t >> 1, j = t & 1;
                int d = d0 + j;
                float gg[4];
#pragma unroll
                for (int q = 0; q < 4; ++q) gg[q] = su.c.accs[bb][q * 2 + j] + bsum[q];
                float gi = sigm(gg[0]), gf = sigm(gg[1]), gn = tanhf(gg[2]), go = sigm(gg[3]);
                float cn = gf * g.c_buf[bb * 512 + d] + gi * gn;
                g.c_buf[bb * 512 + d] = cn;
                float h = go * tanhf(cn);
                g.h_buf[(par ^ 1) * B_ * H_ + bb * 512 + d] = h;
                g.hze[(size_t)(bb * T_ + step) * 1280 + d] = f2bf(h);
            }
        }
        gridbar(g.bar, (++phase) * GRID_);
    }
}

extern "C" void kernel_launch(void* const* d_in, const int* in_sizes, int n_in,
                              void* d_out, int out_size, void* d_ws, size_t ws_size,
                              hipStream_t stream) {
    (void)in_sizes; (void)n_in; (void)out_size; (void)ws_size;
    const int* y = (const int*)d_in[3];

    char* base = (char*)d_ws;
    size_t off = 0;
    auto alloc = [&](size_t bytes) {
        void* p = base + off;
        off = (off + bytes + 63) & ~(size_t)63;
        return p;
    };
    // Total footprint 33.63 MB — must stay <= 34.34 MB (round-2 proven bound).
    int* flg   = (int*)alloc(64);
    int* bar   = (int*)alloc(64);
    u16* conv  = (u16*)alloc((size_t)7067000 * 2);
    u16* pre1  = (u16*)alloc((size_t)6272 * 256 * 2);   // t2 aliases after decoder
    u16* hze   = (u16*)alloc((size_t)4096 * 1280 * 2);
    u16* wT    = (u16*)alloc((size_t)2048 * 1280 * 2);  // t1 aliases after decoder
    u16* w1hT  = (u16*)alloc((size_t)256 * 512 * 2);
    float* z_buf = (float*)alloc(32 * 512 * 4);
    float* s_buf = (float*)alloc(32 * 196 * 4);
    float* h_buf = (float*)alloc(2 * 32 * 512 * 4);
    float* c_buf = (float*)alloc(32 * 512 * 4);
    u16* t1 = wT;    // wT dead after decoder; 5.24MB >= 2.93MB
    u16* t2 = pre1;  // pre1 dead after decoder; 3.21MB >= 2.93MB

    u16* c_a     = conv + 0;
    u16* c_h0    = conv + 3211264;
    u16* c_c0    = conv + 3227648;
    u16* c_attw1 = conv + 3244032;
    u16* c_attb1 = conv + 3506176;
    u16* c_attw2 = conv + 3506432;
    u16* c_attb2 = conv + 3539200;
    u16* c_attw3 = conv + 3539328;
    u16* c_wih   = conv + 3539456;
    u16* c_whh   = conv + 5112320;
    u16* c_bih   = conv + 6160896;
    u16* c_bhh   = conv + 6162944;
    u16* c_emb   = conv + 6164992;
    u16* c_ow1   = conv + 6296064;
    u16* c_ob1   = conv + 6754304;
    u16* c_ow2   = conv + 6754664;
    u16* c_ob2   = conv + 6882832;
    u16* c_ow3   = conv + 6883192;
    u16* c_ob3   = conv + 7066488;

    ConvPtrs cp;
    {
        const int idx[19] = {0, 1, 2, 4, 5, 6, 7, 8, 10, 11, 12, 13, 14, 15, 16, 17, 18, 19, 20};
        for (int i = 0; i < 19; ++i) cp.p[i] = d_in[idx[i]];
    }

    detect_kernel<<<1, 64, 0, stream>>>((const u16*)d_in[4], flg, bar);
    conv_kernel<<<6902, 256, 0, stream>>>(cp, flg, conv);
    prep_kernel<<<2304, 256, 0, stream>>>(c_wih, c_whh, c_attw1, wT, w1hT);
    embed_kernel<<<1024, 256, 0, stream>>>(y, c_emb, hze);
    gemm_kernel<false, 1><<<dim3(4, 49), 256, 0, stream>>>(
        c_a, 512, c_attw1, 256, c_attb1, pre1, 256, 6272, 256, 512, flg);

    DecArgs g;
    g.h0 = c_h0; g.c0 = c_c0; g.pre1 = pre1; g.att_w2 = c_attw2; g.att_b2 = c_attb2;
    g.att_w3 = c_attw3; g.w1hT = w1hT; g.wT = wT; g.bih = c_bih; g.bhh = c_bhh;
    g.a = c_a; g.hze = hze; g.z_buf = z_buf; g.s_buf = s_buf; g.h_buf = h_buf;
    g.c_buf = c_buf; g.bar = bar;
    decoder_kernel<<<GRID_, 256, 0, stream>>>(g);

    gemm_kernel<true, 1><<<dim3(6, 32), 256, 0, stream>>>(
        hze, 1280, c_ow1, 358, c_ob1, t1, 358, 4096, 358, 1280, flg);
    gemm_kernel<true, 1><<<dim3(6, 32), 256, 0, stream>>>(
        t1, 358, c_ow2, 358, c_ob2, t2, 358, 4096, 358, 358, flg);
    gemm_kernel<false, 2><<<dim3(8, 32), 256, 0, stream>>>(
        t2, 358, c_ow3, 512, c_ob3, d_out, 512, 4096, 512, 358, flg);
}

// Round 5
// 8760.806 us; speedup vs baseline: 3.0110x; 3.0110x over previous
//
#include <hip/hip_runtime.h>
#include <hip/hip_bf16.h>
#include <cstdint>

#define B_ 32
#define L_ 196
#define D_ 512
#define H_ 512
#define E_ 256
#define T_ 128
#define V_ 512
#define GRID_ 256

using u16 = unsigned short;

__device__ __forceinline__ float bf2f(u16 u) { return __uint_as_float(((unsigned)u) << 16); }
__device__ __forceinline__ u16 f2bf(float f) {
    unsigned u = __float_as_uint(f);
    return (u16)((u + 0x7FFFu + ((u >> 16) & 1u)) >> 16);
}
__device__ __forceinline__ float2 bfp(unsigned u) {
    return make_float2(__uint_as_float(u << 16), __uint_as_float(u & 0xffff0000u));
}
__device__ __forceinline__ float sigm(float x) { return 1.f / (1.f + __expf(-x)); }
__device__ __forceinline__ float tanh_fast(float x) { return 1.f - 2.f / (__expf(2.f * x) + 1.f); }

// --- coherent (cache-bypass) payload access: relaxed agent-scope atomics.
// Writers write-through to the coherence point; readers always fetch fresh.
// No fences anywhere -> no buffer_inv -> read-only tensors stay L2-warm.
__device__ __forceinline__ float ldcf(const float* p) {
    return __hip_atomic_load((float*)p, __ATOMIC_RELAXED, __HIP_MEMORY_SCOPE_AGENT);
}
__device__ __forceinline__ float2 ldcf2(const float* p) {
    unsigned long long v = __hip_atomic_load((unsigned long long*)p, __ATOMIC_RELAXED,
                                             __HIP_MEMORY_SCOPE_AGENT);
    union { unsigned long long u; float2 f; } c; c.u = v; return c.f;
}
__device__ __forceinline__ float4 ldcf4(const float* p) {
    float2 a = ldcf2(p), b = ldcf2(p + 2);
    return make_float4(a.x, a.y, b.x, b.y);
}
__device__ __forceinline__ uint2 ldcu4h(const u16* p) {  // 4 bf16
    unsigned long long v = __hip_atomic_load((unsigned long long*)p, __ATOMIC_RELAXED,
                                             __HIP_MEMORY_SCOPE_AGENT);
    union { unsigned long long u; uint2 f; } c; c.u = v; return c.f;
}
__device__ __forceinline__ void stcf(float* p, float v) {
    __hip_atomic_store(p, v, __ATOMIC_RELAXED, __HIP_MEMORY_SCOPE_AGENT);
}
__device__ __forceinline__ void stcu(unsigned* p, unsigned v) {
    __hip_atomic_store(p, v, __ATOMIC_RELAXED, __HIP_MEMORY_SCOPE_AGENT);
}
__device__ __forceinline__ void stcu64(unsigned long long* p, unsigned long long v) {
    __hip_atomic_store(p, v, __ATOMIC_RELAXED, __HIP_MEMORY_SCOPE_AGENT);
}

// ---------------- dtype detect (bf16 vs fp32 inputs) + barrier reset ----------------
__global__ void detect_kernel(const u16* __restrict__ w, int* __restrict__ flg,
                              int* __restrict__ bar) {
    if (threadIdx.x == 0) {
        int cnt = 0;
        for (int i = 0; i < 64; ++i) {
            int e = (w[i] >> 7) & 0xFF;
            cnt += (e >= 100 && e <= 130);
        }
        flg[0] = (cnt >= 56) ? 1 : 0;
        bar[0] = 0;
    }
}

// ---------------- convert all float tensors to internal bf16 ----------------
struct ConvPtrs { const void* p[19]; };

__global__ __launch_bounds__(256) void conv_kernel(ConvPtrs cp, const int* __restrict__ flg,
                                                   u16* __restrict__ dst) {
    constexpr int NT = 19;
    constexpr unsigned off[NT + 1] = {
        0u, 3211264u, 3227648u, 3244032u, 3506176u, 3506432u, 3539200u, 3539328u,
        3539456u, 5112320u, 6160896u, 6162944u, 6164992u, 6296064u, 6754304u,
        6754664u, 6882832u, 6883192u, 7066488u, 7067000u};
    constexpr unsigned realN[NT] = {
        3211264u, 16384u, 16384u, 262144u, 256u, 32768u, 128u, 128u,
        1572864u, 1048576u, 2048u, 2048u, 131072u, 458240u, 358u,
        128164u, 358u, 183296u, 512u};
    unsigned pos = (blockIdx.x * 256u + threadIdx.x) * 4u;
    if (pos >= off[NT]) return;
    int t = 0;
#pragma unroll
    for (int i = 1; i < NT; ++i) t += (pos >= off[i]);
    unsigned local = pos - off[t];
    int bf = flg[0];
    const void* src = cp.p[t];
    u16* d = dst + off[t];
#pragma unroll
    for (int j = 0; j < 4; ++j) {
        unsigned l = local + j;
        u16 v = 0;
        if (l < realN[t]) v = bf ? ((const u16*)src)[l] : f2bf(((const float*)src)[l]);
        d[l] = v;
    }
}

// ---------------- weight transposes: wT[col][k], w1hT[col][k] ----------------
__global__ __launch_bounds__(256) void prep_kernel(const u16* __restrict__ w_ih,
                                                   const u16* __restrict__ w_hh,
                                                   const u16* __restrict__ att_w1,
                                                   u16* __restrict__ wT,
                                                   u16* __restrict__ w1hT) {
    int c = blockIdx.x, t = threadIdx.x;
    if (c < 2048) {
#pragma unroll
        for (int i = 0; i < 5; ++i) {
            int k = i * 256 + t;
            u16 v = (k < 768) ? w_ih[(size_t)k * 2048 + c] : w_hh[(size_t)(k - 768) * 2048 + c];
            wT[(size_t)c * 1280 + k] = v;
        }
    } else {
        int c2 = c - 2048;
#pragma unroll
        for (int i = 0; i < 2; ++i) {
            int k = i * 256 + t;
            w1hT[(size_t)c2 * 512 + k] = att_w1[(size_t)(512 + k) * 256 + c2];
        }
    }
}

// ---------------- embedding (shifted y) -> hze e-part ----------------
__global__ __launch_bounds__(256) void embed_kernel(const int* __restrict__ y,
                                                    const u16* __restrict__ emb,
                                                    u16* __restrict__ hze) {
    int t = threadIdx.x;
    int row0 = blockIdx.x * 4;
    for (int i = 0; i < 4; ++i) {
        int row = row0 + i;
        int b = row >> 7, tt = row & 127;
        int yin = tt ? y[b * T_ + tt - 1] : 0;
        hze[(size_t)row * 1280 + 1024 + t] = emb[yin * E_ + t];
    }
}

// ---------------- generic tiled GEMM: C = act(A @ Bw + bias) ----------------
template <bool TANH, int OMODE>
__global__ __launch_bounds__(256) void gemm_kernel(const u16* __restrict__ A, int lda,
                                                   const u16* __restrict__ Bw, int ldb,
                                                   const u16* __restrict__ bias,
                                                   void* __restrict__ Cv, int ldc,
                                                   int M, int N, int K,
                                                   const int* __restrict__ flg) {
    __shared__ float As[16][132];
    __shared__ float Bs[16][68];
    int t = threadIdx.x;
    int n0 = blockIdx.x * 64;
    int m0 = blockIdx.y * 128;
    int tx = t & 15, ty = t >> 4;
    float acc[8][4];
#pragma unroll
    for (int i = 0; i < 8; ++i)
#pragma unroll
        for (int j = 0; j < 4; ++j) acc[i][j] = 0.f;

    int ar = t >> 1, akb = (t & 1) * 8;
    int bn = t & 63, bkg = t >> 6;

    for (int k0 = 0; k0 < K; k0 += 16) {
        const u16* Ap = A + (size_t)(m0 + ar) * lda + k0 + akb;
        if (k0 + 16 <= K) {
#pragma unroll
            for (int i = 0; i < 8; ++i) As[akb + i][ar] = bf2f(Ap[i]);
        } else {
#pragma unroll
            for (int i = 0; i < 8; ++i) As[akb + i][ar] = (k0 + akb + i < K) ? bf2f(Ap[i]) : 0.f;
        }
#pragma unroll
        for (int i = 0; i < 4; ++i) {
            int kk = bkg * 4 + i;
            int kg = k0 + kk, ng = n0 + bn;
            Bs[kk][bn] = (kg < K && ng < N) ? bf2f(Bw[(size_t)kg * ldb + ng]) : 0.f;
        }
        __syncthreads();
#pragma unroll
        for (int kk = 0; kk < 16; ++kk) {
            float4 aA = *(const float4*)&As[kk][ty * 8];
            float4 aB = *(const float4*)&As[kk][ty * 8 + 4];
            float4 bv = *(const float4*)&Bs[kk][tx * 4];
            float av[8] = {aA.x, aA.y, aA.z, aA.w, aB.x, aB.y, aB.z, aB.w};
            float bb[4] = {bv.x, bv.y, bv.z, bv.w};
#pragma unroll
            for (int i = 0; i < 8; ++i)
#pragma unroll
                for (int j = 0; j < 4; ++j) acc[i][j] += av[i] * bb[j];
        }
        __syncthreads();
    }
    int obf = (OMODE == 2) ? flg[0] : 1;
    float bb[4];
#pragma unroll
    for (int j = 0; j < 4; ++j) {
        int n = n0 + tx * 4 + j;
        bb[j] = (n < N) ? bf2f(bias[n]) : 0.f;
    }
#pragma unroll
    for (int i = 0; i < 8; ++i) {
        int m = m0 + ty * 8 + i;
#pragma unroll
        for (int j = 0; j < 4; ++j) {
            int n = n0 + tx * 4 + j;
            if (n < N) {
                float v = acc[i][j] + bb[j];
                if (TANH) v = tanhf(v);
                if (OMODE == 1 || obf)
                    ((u16*)Cv)[(size_t)m * ldc + n] = f2bf(v);
                else
                    ((float*)Cv)[(size_t)m * ldc + n] = v;
            }
        }
    }
}

// ---------------- persistent decoder: whole T-loop, 3 grid barriers/step ----------------
struct DecArgs {
    const u16 *h0, *c0, *pre1, *att_w2, *att_b2, *att_w3, *w1hT, *wT, *bih, *bhh, *a;
    u16* hze;
    float *s_buf, *h_buf, *c_buf;
    int* bar;
};

struct SA { float x1s[28][262]; float part[28][36]; };
struct SB { float red[256]; float alpha[200]; float zsh[256]; };
struct SC { float inp[32][132]; float accs[32][9]; float hsh[32][2]; };
union SU { SA a; SB b; SC c; float hs[512]; };

// Fence-free barrier: pure relaxed counter. __syncthreads() drains vmcnt, so all
// waves' write-through payload stores are at the coherence point before the
// leader's add. No buffer_inv is ever emitted -> L2 stays warm for read-only data.
__device__ __forceinline__ void gridbar(int* bar, int target) {
    __syncthreads();
    if (threadIdx.x == 0) {
        __hip_atomic_fetch_add(bar, 1, __ATOMIC_RELAXED, __HIP_MEMORY_SCOPE_AGENT);
        while (__hip_atomic_load(bar, __ATOMIC_RELAXED, __HIP_MEMORY_SCOPE_AGENT) < target)
            __builtin_amdgcn_s_sleep(2);
    }
    __syncthreads();
}

__global__ __launch_bounds__(256) void decoder_kernel(DecArgs g) {
    int blk = blockIdx.x, t = threadIdx.x;
    __shared__ SU su;
    __shared__ u16 wlds[8][1288];
    __shared__ float w3s[128], b2s[128];
    int phase = 0;

    // --- one-time: stage C weight slice (8 gate-cols for d0,d0+1) into LDS ---
    int d0 = blk * 2;
#pragma unroll
    for (int i = 0; i < 5; ++i) {
        int v = i * 256 + t;           // 1280 vec8 total
        int cidx = v / 160, k8 = v % 160;
        int col = (cidx >> 1) * 512 + d0 + (cidx & 1);
        *(uint4*)&wlds[cidx][k8 * 8] = *(const uint4*)(g.wT + (size_t)col * 1280 + k8 * 8);
    }
    if (t < 128) {
        w3s[t] = bf2f(g.att_w3[t]);
        b2s[t] = bf2f(g.att_b2[t]);
    }
    float bsum[4];
    {
        int bj = t & 1;
#pragma unroll
        for (int q = 0; q < 4; ++q) {
            int col = q * 512 + d0 + bj;
            bsum[q] = bf2f(g.bih[col]) + bf2f(g.bhh[col]);
        }
    }
    if (blk < 32) {
        for (int i = t; i < 512; i += 256) {
            stcf(&g.h_buf[blk * 512 + i], bf2f(g.h0[blk * 512 + i]));
            stcf(&g.c_buf[blk * 512 + i], bf2f(g.c0[blk * 512 + i]));
        }
    }
    gridbar(g.bar, (++phase) * GRID_);

    int ab = blk >> 3, ach = blk & 7;
    int anrows = (ach == 7) ? 21 : 25;
    int arow0 = ab * 196 + ach * 25;

    for (int step = 0; step < T_; ++step) {
        int par = step & 1;
        const float* hcur = g.h_buf + par * B_ * H_;
        // ================= stage A: hterm + attention MLP scores =================
        {
            float2 h2 = ldcf2(hcur + ab * 512 + 2 * t);
            su.hs[2 * t] = h2.x;
            su.hs[2 * t + 1] = h2.y;
        }
        __syncthreads();
        float htv;
        {
            float acc = 0.f;
            const u16* wp = g.w1hT + (size_t)t * 512;
#pragma unroll 4
            for (int k = 0; k < 512; k += 8) {
                uint4 wv = *(const uint4*)(wp + k);
                float4 hA = *(const float4*)&su.hs[k];
                float4 hB = *(const float4*)&su.hs[k + 4];
                float2 w01 = bfp(wv.x), w23 = bfp(wv.y), w45 = bfp(wv.z), w67 = bfp(wv.w);
                acc += hA.x * w01.x + hA.y * w01.y + hA.z * w23.x + hA.w * w23.y +
                       hB.x * w45.x + hB.y * w45.y + hB.z * w67.x + hB.w * w67.y;
            }
            htv = acc;
        }
        __syncthreads();  // hs dead; reuse region as x1s
        for (int r = 0; r < 28; ++r) {
            float v = 0.f;
            if (r < anrows) v = tanh_fast(bf2f(g.pre1[(size_t)(arow0 + r) * 256 + t]) + htv);
            su.a.x1s[r][t] = v;
        }
        __syncthreads();
        if (t < 224) {
            int r0 = (t >> 5) * 4, c0v = (t & 31) * 4;
            float acc[4][4];
#pragma unroll
            for (int i = 0; i < 4; ++i)
#pragma unroll
                for (int j = 0; j < 4; ++j) acc[i][j] = 0.f;
            for (int k = 0; k < 256; k += 2) {
                float av[4][2];
#pragma unroll
                for (int i = 0; i < 4; ++i) {
                    float2 v = *(const float2*)&su.a.x1s[r0 + i][k];
                    av[i][0] = v.x;
                    av[i][1] = v.y;
                }
#pragma unroll
                for (int u = 0; u < 2; ++u) {
                    const u16* wp2 = g.att_w2 + (size_t)(k + u) * 128 + c0v;
#pragma unroll
                    for (int j = 0; j < 4; ++j) {
                        float w = bf2f(wp2[j]);
#pragma unroll
                        for (int i = 0; i < 4; ++i) acc[i][j] += av[i][u] * w;
                    }
                }
            }
#pragma unroll
            for (int i = 0; i < 4; ++i) {
                float p = 0.f;
#pragma unroll
                for (int j = 0; j < 4; ++j)
                    p += tanh_fast(acc[i][j] + b2s[c0v + j]) * w3s[c0v + j];
                su.a.part[r0 + i][t & 31] = p;
            }
        }
        __syncthreads();
        if (t < anrows) {
            float s = 0.f;
#pragma unroll
            for (int cg = 0; cg < 32; ++cg) s += su.a.part[t][cg];
            stcf(&g.s_buf[arow0 + t], s);  // att_b3 omitted: softmax-invariant
        }
        gridbar(g.bar, (++phase) * GRID_);
        // ================= stage B: softmax + context z =================
        if (blk < 64) {
            int b = blk >> 1, half = blk & 1;
            float v = (t < L_) ? ldcf(&g.s_buf[b * L_ + t]) : -1e30f;
            su.b.red[t] = v;
            __syncthreads();
            for (int off = 128; off > 0; off >>= 1) {
                if (t < off) su.b.red[t] = fmaxf(su.b.red[t], su.b.red[t + off]);
                __syncthreads();
            }
            float mx = su.b.red[0];
            __syncthreads();
            float e = (t < L_) ? __expf(v - mx) : 0.f;
            su.b.red[t] = e;
            __syncthreads();
            for (int off = 128; off > 0; off >>= 1) {
                if (t < off) su.b.red[t] += su.b.red[t + off];
                __syncthreads();
            }
            float inv = 1.f / su.b.red[0];
            __syncthreads();
            if (t < L_) su.b.alpha[t] = e * inv;
            __syncthreads();
            int d = half * 256 + t;
            const u16* ap = g.a + (size_t)b * L_ * 512 + d;
            float z = 0.f;
            for (int l = 0; l < L_; ++l) z += su.b.alpha[l] * bf2f(ap[(size_t)l * 512]);
            su.b.zsh[t] = z;
            __syncthreads();
            if (t < 128) {
                unsigned pk = (unsigned)f2bf(su.b.zsh[2 * t]) |
                              ((unsigned)f2bf(su.b.zsh[2 * t + 1]) << 16);
                stcu((unsigned*)(g.hze + (size_t)(b * T_ + step) * 1280 + 512 + half * 256 + 2 * t),
                     pk);
            }
        }
        gridbar(g.bar, (++phase) * GRID_);
        // ================= stage C: LSTM gates + state update =================
        {
            int cb = t >> 3, cc = t & 7;
            float acc = 0.f;
            for (int ck = 0; ck < 10; ++ck) {
                __syncthreads();
#pragma unroll
                for (int i = 0; i < 4; ++i) {
                    int v = i * 256 + t;       // 1024 vec4 = 32b x 128k
                    int bb = v >> 5;
                    int kk = (v & 31) * 4;
                    float4 val;
                    if (ck < 4) {
                        uint2 zv = ldcu4h(g.hze + (size_t)(bb * T_ + step) * 1280 + 512 +
                                          ck * 128 + kk);
                        float2 p0 = bfp(zv.x), p1 = bfp(zv.y);
                        val = make_float4(p0.x, p0.y, p1.x, p1.y);
                    } else if (ck < 6) {
                        const u16* ep = g.hze + (size_t)(bb * T_ + step) * 1280 + 1024 +
                                        (ck - 4) * 128 + kk;
                        val.x = bf2f(ep[0]); val.y = bf2f(ep[1]);
                        val.z = bf2f(ep[2]); val.w = bf2f(ep[3]);
                    } else {
                        val = ldcf4(g.h_buf + par * B_ * H_ + bb * 512 + (ck - 6) * 128 + kk);
                    }
                    *(float4*)&su.c.inp[bb][kk] = val;
                }
                __syncthreads();
                const u16* wrow = &wlds[cc][ck * 128];
                const float* irow = &su.c.inp[cb][0];
#pragma unroll 8
                for (int kk = 0; kk < 128; kk += 4) {
                    float4 iv = *(const float4*)(irow + kk);
                    uint2 wv = *(const uint2*)(wrow + kk);
                    float2 w01 = bfp(wv.x), w23 = bfp(wv.y);
                    acc += iv.x * w01.x + iv.y * w01.y + iv.z * w23.x + iv.w * w23.y;
                }
            }
            __syncthreads();
            su.c.accs[cb][cc] = acc;
            __syncthreads();
            if (t < 64) {
                int bb = t >> 1, j = t & 1;
                int d = d0 + j;
                float gg[4];
#pragma unroll
                for (int q = 0; q < 4; ++q) gg[q] = su.c.accs[bb][q * 2 + j] + bsum[q];
                float gi = sigm(gg[0]), gf = sigm(gg[1]);
                float gn = tanh_fast(gg[2]), go = sigm(gg[3]);
                float cn = gf * g.c_buf[bb * 512 + d] + gi * gn;
                g.c_buf[bb * 512 + d] = cn;   // block-private: plain is safe
                su.c.hsh[bb][j] = go * tanh_fast(cn);
            }
            __syncthreads();
            if (t < 64 && (t & 1) == 0) {
                int bb = t >> 1;
                float2 hp = *(float2*)&su.c.hsh[bb][0];
                union { float2 f; unsigned long long u; } cv; cv.f = hp;
                stcu64((unsigned long long*)(g.h_buf + (par ^ 1) * B_ * H_ + bb * 512 + d0), cv.u);
                unsigned pk = (unsigned)f2bf(hp.x) | ((unsigned)f2bf(hp.y) << 16);
                stcu((unsigned*)(g.hze + (size_t)(bb * T_ + step) * 1280 + d0), pk);
            }
        }
        gridbar(g.bar, (++phase) * GRID_);
    }
}

extern "C" void kernel_launch(void* const* d_in, const int* in_sizes, int n_in,
                              void* d_out, int out_size, void* d_ws, size_t ws_size,
                              hipStream_t stream) {
    (void)in_sizes; (void)n_in; (void)out_size; (void)ws_size;
    const int* y = (const int*)d_in[3];

    char* base = (char*)d_ws;
    size_t off = 0;
    auto alloc = [&](size_t bytes) {
        void* p = base + off;
        off = (off + bytes + 63) & ~(size_t)63;
        return p;
    };
    // Total footprint ~33.5 MB — must stay <= 34.34 MB (round-2 proven bound).
    int* flg   = (int*)alloc(64);
    int* bar   = (int*)alloc(64);
    u16* conv  = (u16*)alloc((size_t)7067000 * 2);
    u16* pre1  = (u16*)alloc((size_t)6272 * 256 * 2);   // t2 aliases after decoder
    u16* hze   = (u16*)alloc((size_t)4096 * 1280 * 2);
    u16* wT    = (u16*)alloc((size_t)2048 * 1280 * 2);  // t1 aliases after decoder
    u16* w1hT  = (u16*)alloc((size_t)256 * 512 * 2);
    float* s_buf = (float*)alloc(32 * 196 * 4);
    float* h_buf = (float*)alloc(2 * 32 * 512 * 4);
    float* c_buf = (float*)alloc(32 * 512 * 4);
    u16* t1 = wT;    // wT dead after decoder; 5.24MB >= 2.93MB
    u16* t2 = pre1;  // pre1 dead after decoder; 3.21MB >= 2.93MB

    u16* c_a     = conv + 0;
    u16* c_h0    = conv + 3211264;
    u16* c_c0    = conv + 3227648;
    u16* c_attw1 = conv + 3244032;
    u16* c_attb1 = conv + 3506176;
    u16* c_attw2 = conv + 3506432;
    u16* c_attb2 = conv + 3539200;
    u16* c_attw3 = conv + 3539328;
    u16* c_wih   = conv + 3539456;
    u16* c_whh   = conv + 5112320;
    u16* c_bih   = conv + 6160896;
    u16* c_bhh   = conv + 6162944;
    u16* c_emb   = conv + 6164992;
    u16* c_ow1   = conv + 6296064;
    u16* c_ob1   = conv + 6754304;
    u16* c_ow2   = conv + 6754664;
    u16* c_ob2   = conv + 6882832;
    u16* c_ow3   = conv + 6883192;
    u16* c_ob3   = conv + 7066488;

    ConvPtrs cp;
    {
        const int idx[19] = {0, 1, 2, 4, 5, 6, 7, 8, 10, 11, 12, 13, 14, 15, 16, 17, 18, 19, 20};
        for (int i = 0; i < 19; ++i) cp.p[i] = d_in[idx[i]];
    }

    detect_kernel<<<1, 64, 0, stream>>>((const u16*)d_in[4], flg, bar);
    conv_kernel<<<6902, 256, 0, stream>>>(cp, flg, conv);
    prep_kernel<<<2304, 256, 0, stream>>>(c_wih, c_whh, c_attw1, wT, w1hT);
    embed_kernel<<<1024, 256, 0, stream>>>(y, c_emb, hze);
    gemm_kernel<false, 1><<<dim3(4, 49), 256, 0, stream>>>(
        c_a, 512, c_attw1, 256, c_attb1, pre1, 256, 6272, 256, 512, flg);

    DecArgs g;
    g.h0 = c_h0; g.c0 = c_c0; g.pre1 = pre1; g.att_w2 = c_attw2; g.att_b2 = c_attb2;
    g.att_w3 = c_attw3; g.w1hT = w1hT; g.wT = wT; g.bih = c_bih; g.bhh = c_bhh;
    g.a = c_a; g.hze = hze; g.s_buf = s_buf; g.h_buf = h_buf;
    g.c_buf = c_buf; g.bar = bar;
    decoder_kernel<<<GRID_, 256, 0, stream>>>(g);

    gemm_kernel<true, 1><<<dim3(6, 32), 256, 0, stream>>>(
        hze, 1280, c_ow1, 358, c_ob1, t1, 358, 4096, 358, 1280, flg);
    gemm_kernel<true, 1><<<dim3(6, 32), 256, 0, stream>>>(
        t1, 358, c_ow2, 358, c_ob2, t2, 358, 4096, 358, 358, flg);
    gemm_kernel<false, 2><<<dim3(8, 32), 256, 0, stream>>>(
        t2, 358, c_ow3, 512, c_ob3, d_out, 512, 4096, 512, 358, flg);
}

// Round 6
// 7090.488 us; speedup vs baseline: 3.7203x; 1.2356x over previous
//
#include <hip/hip_runtime.h>
#include <hip/hip_bf16.h>
#include <cstdint>

#define B_ 32
#define L_ 196
#define D_ 512
#define H_ 512
#define E_ 256
#define T_ 128
#define V_ 512
#define GRID_ 256

using u16 = unsigned short;

__device__ __forceinline__ float bf2f(u16 u) { return __uint_as_float(((unsigned)u) << 16); }
__device__ __forceinline__ u16 f2bf(float f) {
    unsigned u = __float_as_uint(f);
    return (u16)((u + 0x7FFFu + ((u >> 16) & 1u)) >> 16);
}
__device__ __forceinline__ float2 bfp(unsigned u) {
    return make_float2(__uint_as_float(u << 16), __uint_as_float(u & 0xffff0000u));
}
__device__ __forceinline__ float sigm(float x) { return 1.f / (1.f + __expf(-x)); }
__device__ __forceinline__ float tanh_fast(float x) { return 1.f - 2.f / (__expf(2.f * x) + 1.f); }

// --- coherent (cache-bypass) payload access: relaxed agent-scope atomics.
__device__ __forceinline__ float ldcf(const float* p) {
    return __hip_atomic_load((float*)p, __ATOMIC_RELAXED, __HIP_MEMORY_SCOPE_AGENT);
}
__device__ __forceinline__ unsigned ldc32(const void* p) {
    return __hip_atomic_load((unsigned*)p, __ATOMIC_RELAXED, __HIP_MEMORY_SCOPE_AGENT);
}
__device__ __forceinline__ uint2 ldcu4h(const u16* p) {  // 4 bf16 (8B)
    unsigned long long v = __hip_atomic_load((unsigned long long*)p, __ATOMIC_RELAXED,
                                             __HIP_MEMORY_SCOPE_AGENT);
    union { unsigned long long u; uint2 f; } c; c.u = v; return c.f;
}
__device__ __forceinline__ void stcf(float* p, float v) {
    __hip_atomic_store(p, v, __ATOMIC_RELAXED, __HIP_MEMORY_SCOPE_AGENT);
}
__device__ __forceinline__ void stcu(unsigned* p, unsigned v) {
    __hip_atomic_store(p, v, __ATOMIC_RELAXED, __HIP_MEMORY_SCOPE_AGENT);
}

// ---------------- dtype detect + barrier-tree reset ----------------
__global__ void detect_kernel(const u16* __restrict__ w, int* __restrict__ flg,
                              int* __restrict__ bars) {
    for (int i = threadIdx.x; i < 1056; i += 64) bars[i] = 0;
    if (threadIdx.x == 0) {
        int cnt = 0;
        for (int i = 0; i < 64; ++i) {
            int e = (w[i] >> 7) & 0xFF;
            cnt += (e >= 100 && e <= 130);
        }
        flg[0] = (cnt >= 56) ? 1 : 0;
    }
}

// ---------------- convert all float tensors to internal bf16 ----------------
struct ConvPtrs { const void* p[19]; };

__global__ __launch_bounds__(256) void conv_kernel(ConvPtrs cp, const int* __restrict__ flg,
                                                   u16* __restrict__ dst) {
    constexpr int NT = 19;
    constexpr unsigned off[NT + 1] = {
        0u, 3211264u, 3227648u, 3244032u, 3506176u, 3506432u, 3539200u, 3539328u,
        3539456u, 5112320u, 6160896u, 6162944u, 6164992u, 6296064u, 6754304u,
        6754664u, 6882832u, 6883192u, 7066488u, 7067000u};
    constexpr unsigned realN[NT] = {
        3211264u, 16384u, 16384u, 262144u, 256u, 32768u, 128u, 128u,
        1572864u, 1048576u, 2048u, 2048u, 131072u, 458240u, 358u,
        128164u, 358u, 183296u, 512u};
    unsigned pos = (blockIdx.x * 256u + threadIdx.x) * 4u;
    if (pos >= off[NT]) return;
    int t = 0;
#pragma unroll
    for (int i = 1; i < NT; ++i) t += (pos >= off[i]);
    unsigned local = pos - off[t];
    int bf = flg[0];
    const void* src = cp.p[t];
    u16* d = dst + off[t];
#pragma unroll
    for (int j = 0; j < 4; ++j) {
        unsigned l = local + j;
        u16 v = 0;
        if (l < realN[t]) v = bf ? ((const u16*)src)[l] : f2bf(((const float*)src)[l]);
        d[l] = v;
    }
}

// ---------------- weight transposes: wT, w1hT, w2T ----------------
__global__ __launch_bounds__(256) void prep_kernel(const u16* __restrict__ w_ih,
                                                   const u16* __restrict__ w_hh,
                                                   const u16* __restrict__ att_w1,
                                                   const u16* __restrict__ att_w2,
                                                   u16* __restrict__ wT,
                                                   u16* __restrict__ w1hT,
                                                   u16* __restrict__ w2T) {
    int c = blockIdx.x, t = threadIdx.x;
    if (c < 2048) {
#pragma unroll
        for (int i = 0; i < 5; ++i) {
            int k = i * 256 + t;
            u16 v = (k < 768) ? w_ih[(size_t)k * 2048 + c] : w_hh[(size_t)(k - 768) * 2048 + c];
            wT[(size_t)c * 1280 + k] = v;
        }
    } else if (c < 2304) {
        int c2 = c - 2048;
#pragma unroll
        for (int i = 0; i < 2; ++i) {
            int k = i * 256 + t;
            w1hT[(size_t)c2 * 512 + k] = att_w1[(size_t)(512 + k) * 256 + c2];
        }
    } else {
        int c3 = c - 2304;
        w2T[c3 * 256 + t] = att_w2[(size_t)t * 128 + c3];
    }
}

// ---------------- embedding (shifted y) -> hze e-part ----------------
__global__ __launch_bounds__(256) void embed_kernel(const int* __restrict__ y,
                                                    const u16* __restrict__ emb,
                                                    u16* __restrict__ hze) {
    int t = threadIdx.x;
    int row0 = blockIdx.x * 4;
    for (int i = 0; i < 4; ++i) {
        int row = row0 + i;
        int b = row >> 7, tt = row & 127;
        int yin = tt ? y[b * T_ + tt - 1] : 0;
        hze[(size_t)row * 1280 + 1024 + t] = emb[yin * E_ + t];
    }
}

// ---------------- generic tiled GEMM: C = act(A @ Bw + bias) ----------------
template <bool TANH, int OMODE>
__global__ __launch_bounds__(256) void gemm_kernel(const u16* __restrict__ A, int lda,
                                                   const u16* __restrict__ Bw, int ldb,
                                                   const u16* __restrict__ bias,
                                                   void* __restrict__ Cv, int ldc,
                                                   int M, int N, int K,
                                                   const int* __restrict__ flg) {
    __shared__ float As[16][132];
    __shared__ float Bs[16][68];
    int t = threadIdx.x;
    int n0 = blockIdx.x * 64;
    int m0 = blockIdx.y * 128;
    int tx = t & 15, ty = t >> 4;
    float acc[8][4];
#pragma unroll
    for (int i = 0; i < 8; ++i)
#pragma unroll
        for (int j = 0; j < 4; ++j) acc[i][j] = 0.f;

    int ar = t >> 1, akb = (t & 1) * 8;
    int bn = t & 63, bkg = t >> 6;

    for (int k0 = 0; k0 < K; k0 += 16) {
        const u16* Ap = A + (size_t)(m0 + ar) * lda + k0 + akb;
        if (k0 + 16 <= K) {
#pragma unroll
            for (int i = 0; i < 8; ++i) As[akb + i][ar] = bf2f(Ap[i]);
        } else {
#pragma unroll
            for (int i = 0; i < 8; ++i) As[akb + i][ar] = (k0 + akb + i < K) ? bf2f(Ap[i]) : 0.f;
        }
#pragma unroll
        for (int i = 0; i < 4; ++i) {
            int kk = bkg * 4 + i;
            int kg = k0 + kk, ng = n0 + bn;
            Bs[kk][bn] = (kg < K && ng < N) ? bf2f(Bw[(size_t)kg * ldb + ng]) : 0.f;
        }
        __syncthreads();
#pragma unroll
        for (int kk = 0; kk < 16; ++kk) {
            float4 aA = *(const float4*)&As[kk][ty * 8];
            float4 aB = *(const float4*)&As[kk][ty * 8 + 4];
            float4 bv = *(const float4*)&Bs[kk][tx * 4];
            float av[8] = {aA.x, aA.y, aA.z, aA.w, aB.x, aB.y, aB.z, aB.w};
            float bb[4] = {bv.x, bv.y, bv.z, bv.w};
#pragma unroll
            for (int i = 0; i < 8; ++i)
#pragma unroll
                for (int j = 0; j < 4; ++j) acc[i][j] += av[i] * bb[j];
        }
        __syncthreads();
    }
    int obf = (OMODE == 2) ? flg[0] : 1;
    float bb[4];
#pragma unroll
    for (int j = 0; j < 4; ++j) {
        int n = n0 + tx * 4 + j;
        bb[j] = (n < N) ? bf2f(bias[n]) : 0.f;
    }
#pragma unroll
    for (int i = 0; i < 8; ++i) {
        int m = m0 + ty * 8 + i;
#pragma unroll
        for (int j = 0; j < 4; ++j) {
            int n = n0 + tx * 4 + j;
            if (n < N) {
                float v = acc[i][j] + bb[j];
                if (TANH) v = tanhf(v);
                if (OMODE == 1 || obf)
                    ((u16*)Cv)[(size_t)m * ldc + n] = f2bf(v);
                else
                    ((float*)Cv)[(size_t)m * ldc + n] = v;
            }
        }
    }
}

// ---------------- persistent decoder ----------------
struct DecArgs {
    const u16 *h0, *c0, *pre1, *w2T, *att_b2, *att_w3, *w1hT, *wT, *bih, *bhh, *a;
    u16 *hze, *h0b;
    float *s_buf, *c_buf;
    int* bars;
};

struct SA { float x1s[28][264]; float part[28][36]; };
struct SB { float red[256]; float alpha[200]; float zred[64][5]; };
struct SC { unsigned inp[32][68]; float accs[32][9]; float hsh[32][2]; };
union SU { SA a; SB b; SC c; float hs[512]; };

// Two-level tree barrier, all relaxed, monotonic epochs.
// bars layout (int units): group g arrival at g*32 (g<16); global at 512;
// release replica r at (17+r)*32. Each line has <=16 contenders.
__device__ __forceinline__ void gridbar(int* bars, int blk, int epoch) {
    __syncthreads();
    if (threadIdx.x == 0) {
        int gidx = blk & 15;
        int old = __hip_atomic_fetch_add(&bars[gidx << 5], 1, __ATOMIC_RELAXED,
                                         __HIP_MEMORY_SCOPE_AGENT);
        if (old == epoch * 16 - 1) {  // last arrival of this group for this epoch
            int og = __hip_atomic_fetch_add(&bars[512], 1, __ATOMIC_RELAXED,
                                            __HIP_MEMORY_SCOPE_AGENT);
            if (og == epoch * 16 - 1) {  // last group overall -> broadcast release
#pragma unroll
                for (int r = 0; r < 16; ++r)
                    __hip_atomic_store(&bars[(17 + r) << 5], epoch, __ATOMIC_RELAXED,
                                       __HIP_MEMORY_SCOPE_AGENT);
            }
        }
        while (__hip_atomic_load(&bars[(17 + gidx) << 5], __ATOMIC_RELAXED,
                                 __HIP_MEMORY_SCOPE_AGENT) < epoch)
            __builtin_amdgcn_s_sleep(1);
    }
    __syncthreads();
}

__global__ __launch_bounds__(256) void decoder_kernel(DecArgs g) {
    int blk = blockIdx.x, t = threadIdx.x;
    __shared__ SU su;
    __shared__ u16 wlds[8][1288];
    __shared__ float w3s[128], b2s[128];
    int epoch = 0;

    int d0 = blk * 2;
#pragma unroll
    for (int i = 0; i < 5; ++i) {
        int v = i * 256 + t;           // 1280 vec8 total
        int cidx = v / 160, k8 = v % 160;
        int col = (cidx >> 1) * 512 + d0 + (cidx & 1);
        *(uint4*)&wlds[cidx][k8 * 8] = *(const uint4*)(g.wT + (size_t)col * 1280 + k8 * 8);
    }
    if (t < 128) {
        w3s[t] = bf2f(g.att_w3[t]);
        b2s[t] = bf2f(g.att_b2[t]);
    }
    float bsum[4];
    {
        int bj = t & 1;
#pragma unroll
        for (int q = 0; q < 4; ++q) {
            int col = q * 512 + d0 + bj;
            bsum[q] = bf2f(g.bih[col]) + bf2f(g.bhh[col]);
        }
    }
    if (blk < 32) {
        for (int i = t; i < 512; i += 256)
            stcf(&g.c_buf[blk * 512 + i], bf2f(g.c0[blk * 512 + i]));
        // h0 -> packed bf16 h0b
        unsigned pk = (unsigned)g.h0[blk * 512 + 2 * t] |
                      ((unsigned)g.h0[blk * 512 + 2 * t + 1] << 16);
        stcu((unsigned*)(g.h0b + blk * 512 + 2 * t), pk);
    }
    gridbar(g.bars, blk, ++epoch);

    int ab = blk >> 3, ach = blk & 7;
    int anrows = (ach == 7) ? 21 : 25;
    int arow0 = ab * 196 + ach * 25;

    for (int step = 0; step < T_; ++step) {
        // ================= stage A: hterm + attention MLP scores =================
        const u16* hsrcA = step ? (g.hze + (size_t)(ab * T_ + step - 1) * 1280)
                                : (g.h0b + ab * 512);
        {
            float2 hp = bfp(ldc32(hsrcA + 2 * t));
            su.hs[2 * t] = hp.x;
            su.hs[2 * t + 1] = hp.y;
        }
        __syncthreads();
        float htv;
        {
            float acc = 0.f;
            const u16* wp = g.w1hT + (size_t)t * 512;
#pragma unroll 4
            for (int k = 0; k < 512; k += 8) {
                uint4 wv = *(const uint4*)(wp + k);
                float4 hA = *(const float4*)&su.hs[k];
                float4 hB = *(const float4*)&su.hs[k + 4];
                float2 w01 = bfp(wv.x), w23 = bfp(wv.y), w45 = bfp(wv.z), w67 = bfp(wv.w);
                acc += hA.x * w01.x + hA.y * w01.y + hA.z * w23.x + hA.w * w23.y +
                       hB.x * w45.x + hB.y * w45.y + hB.z * w67.x + hB.w * w67.y;
            }
            htv = acc;
        }
        __syncthreads();  // hs dead; reuse region as x1s
        for (int r = 0; r < 28; ++r) {
            float v = 0.f;
            if (r < anrows) v = tanh_fast(bf2f(g.pre1[(size_t)(arow0 + r) * 256 + t]) + htv);
            su.a.x1s[r][t] = v;
        }
        __syncthreads();
        if (t < 224) {
            int r0 = (t >> 5) * 4, c0v = (t & 31) * 4;
            float acc[4][4];
#pragma unroll
            for (int i = 0; i < 4; ++i)
#pragma unroll
                for (int j = 0; j < 4; ++j) acc[i][j] = 0.f;
            for (int k8 = 0; k8 < 256; k8 += 8) {
                uint4 wv[4];
#pragma unroll
                for (int j = 0; j < 4; ++j)
                    wv[j] = *(const uint4*)(g.w2T + (size_t)(c0v + j) * 256 + k8);
                float4 xa[4], xb[4];
#pragma unroll
                for (int i = 0; i < 4; ++i) {
                    xa[i] = *(const float4*)&su.a.x1s[r0 + i][k8];
                    xb[i] = *(const float4*)&su.a.x1s[r0 + i][k8 + 4];
                }
#pragma unroll
                for (int j = 0; j < 4; ++j) {
                    float2 w0 = bfp(wv[j].x), w1 = bfp(wv[j].y);
                    float2 w2 = bfp(wv[j].z), w3 = bfp(wv[j].w);
#pragma unroll
                    for (int i = 0; i < 4; ++i)
                        acc[i][j] += xa[i].x * w0.x + xa[i].y * w0.y + xa[i].z * w1.x +
                                     xa[i].w * w1.y + xb[i].x * w2.x + xb[i].y * w2.y +
                                     xb[i].z * w3.x + xb[i].w * w3.y;
                }
            }
#pragma unroll
            for (int i = 0; i < 4; ++i) {
                float p = 0.f;
#pragma unroll
                for (int j = 0; j < 4; ++j)
                    p += tanh_fast(acc[i][j] + b2s[c0v + j]) * w3s[c0v + j];
                su.a.part[r0 + i][t & 31] = p;
            }
        }
        __syncthreads();
        if (t < anrows) {
            float s = 0.f;
#pragma unroll
            for (int cg = 0; cg < 32; ++cg) s += su.a.part[t][cg];
            stcf(&g.s_buf[arow0 + t], s);  // att_b3 omitted: softmax-invariant
        }
        gridbar(g.bars, blk, ++epoch);
        // ================= stage B: softmax + context z (all 256 blocks) =========
        {
            float v = (t < L_) ? ldcf(&g.s_buf[ab * L_ + t]) : -1e30f;
            su.b.red[t] = v;
            __syncthreads();
            for (int off = 128; off > 0; off >>= 1) {
                if (t < off) su.b.red[t] = fmaxf(su.b.red[t], su.b.red[t + off]);
                __syncthreads();
            }
            float mx = su.b.red[0];
            __syncthreads();
            float e = (t < L_) ? __expf(v - mx) : 0.f;
            su.b.red[t] = e;
            __syncthreads();
            for (int off = 128; off > 0; off >>= 1) {
                if (t < off) su.b.red[t] += su.b.red[t + off];
                __syncthreads();
            }
            float inv = 1.f / su.b.red[0];
            __syncthreads();
            if (t < L_) su.b.alpha[t] = e * inv;
            __syncthreads();
            int dl = t >> 2, lq = t & 3;
            const u16* ap = g.a + (size_t)ab * L_ * 512 + ach * 64 + dl;
            float zp = 0.f;
            int l0 = lq * 49;
            for (int l = l0; l < l0 + 49; ++l) zp += su.b.alpha[l] * bf2f(ap[(size_t)l * 512]);
            su.b.zred[dl][lq] = zp;
            __syncthreads();
            if (t < 32) {
                float z0 = su.b.zred[2 * t][0] + su.b.zred[2 * t][1] +
                           su.b.zred[2 * t][2] + su.b.zred[2 * t][3];
                float z1 = su.b.zred[2 * t + 1][0] + su.b.zred[2 * t + 1][1] +
                           su.b.zred[2 * t + 1][2] + su.b.zred[2 * t + 1][3];
                unsigned pk = (unsigned)f2bf(z0) | ((unsigned)f2bf(z1) << 16);
                stcu((unsigned*)(g.hze + (size_t)(ab * T_ + step) * 1280 + 512 + ach * 64 + 2 * t),
                     pk);
            }
        }
        gridbar(g.bars, blk, ++epoch);
        // ================= stage C: LSTM gates + state update =================
        {
            int cb = t >> 3, cc = t & 7;
            float acc = 0.f;
            uint2 raw[4];
            auto issueo = [&](int ck) {
#pragma unroll
                for (int i = 0; i < 4; ++i) {
                    int v = i * 256 + t, bb = v >> 5, kk = (v & 31) * 4;
                    if (ck < 4) {
                        raw[i] = ldcu4h(g.hze + (size_t)(bb * T_ + step) * 1280 + 512 +
                                        ck * 128 + kk);
                    } else if (ck < 6) {
                        raw[i] = *(const uint2*)(g.hze + (size_t)(bb * T_ + step) * 1280 + 1024 +
                                                 (ck - 4) * 128 + kk);  // e: plain cached
                    } else {
                        const u16* hp = step ? (g.hze + (size_t)(bb * T_ + step - 1) * 1280)
                                             : (g.h0b + bb * 512);
                        raw[i] = ldcu4h(hp + (ck - 6) * 128 + kk);
                    }
                }
            };
            issueo(0);
            for (int ck = 0; ck < 10; ++ck) {
                __syncthreads();
#pragma unroll
                for (int i = 0; i < 4; ++i) {
                    int v = i * 256 + t, bb = v >> 5, k2 = (v & 31) * 2;
                    *(uint2*)&su.c.inp[bb][k2] = raw[i];
                }
                if (ck < 9) issueo(ck + 1);
                __syncthreads();
                const u16* wrow = &wlds[cc][ck * 128];
                const unsigned* irow = &su.c.inp[cb][0];
#pragma unroll
                for (int k8 = 0; k8 < 16; ++k8) {
                    uint4 iv = *(const uint4*)(irow + k8 * 4);
                    uint4 wv = *(const uint4*)(wrow + k8 * 8);
                    float2 i0 = bfp(iv.x), i1 = bfp(iv.y), i2 = bfp(iv.z), i3 = bfp(iv.w);
                    float2 w0 = bfp(wv.x), w1 = bfp(wv.y), w2 = bfp(wv.z), w3 = bfp(wv.w);
                    acc += i0.x * w0.x + i0.y * w0.y + i1.x * w1.x + i1.y * w1.y +
                           i2.x * w2.x + i2.y * w2.y + i3.x * w3.x + i3.y * w3.y;
                }
            }
            __syncthreads();
            su.c.accs[cb][cc] = acc;
            __syncthreads();
            if (t < 64) {
                int bb = t >> 1, j = t & 1;
                int d = d0 + j;
                float gg[4];
#pragma unroll
                for (int q = 0; q < 4; ++q) gg[q] = su.c.accs[bb][q * 2 + j] + bsum[q];
                float gi = sigm(gg[0]), gf = sigm(gg[1]);
                float gn = tanh_fast(gg[2]), go = sigm(gg[3]);
                float cn = gf * g.c_buf[bb * 512 + d] + gi * gn;
                g.c_buf[bb * 512 + d] = cn;   // block-private: plain is safe
                su.c.hsh[bb][j] = go * tanh_fast(cn);
            }
            __syncthreads();
            if (t < 64 && !(t & 1)) {
                int bb = t >> 1;
                float2 hp = *(float2*)&su.c.hsh[bb][0];
                unsigned pk = (unsigned)f2bf(hp.x) | ((unsigned)f2bf(hp.y) << 16);
                stcu((unsigned*)(g.hze + (size_t)(bb * T_ + step) * 1280 + d0), pk);
            }
        }
        gridbar(g.bars, blk, ++epoch);
    }
}

extern "C" void kernel_launch(void* const* d_in, const int* in_sizes, int n_in,
                              void* d_out, int out_size, void* d_ws, size_t ws_size,
                              hipStream_t stream) {
    (void)in_sizes; (void)n_in; (void)out_size; (void)ws_size;
    const int* y = (const int*)d_in[3];

    char* base = (char*)d_ws;
    size_t off = 0;
    auto alloc = [&](size_t bytes) {
        void* p = base + off;
        off = (off + bytes + 63) & ~(size_t)63;
        return p;
    };
    // Total footprint ~33.6 MB — must stay <= 34.34 MB (round-2 proven bound).
    int* flg   = (int*)alloc(64);
    int* bars  = (int*)alloc(1056 * 4);
    u16* conv  = (u16*)alloc((size_t)7067000 * 2);
    u16* pre1  = (u16*)alloc((size_t)6272 * 256 * 2);   // t2 aliases after decoder
    u16* hze   = (u16*)alloc((size_t)4096 * 1280 * 2);
    u16* wT    = (u16*)alloc((size_t)2048 * 1280 * 2);  // t1 aliases after decoder
    u16* w1hT  = (u16*)alloc((size_t)256 * 512 * 2);
    u16* w2T   = (u16*)alloc((size_t)128 * 256 * 2);
    u16* h0b   = (u16*)alloc((size_t)32 * 512 * 2);
    float* s_buf = (float*)alloc(32 * 196 * 4);
    float* c_buf = (float*)alloc(32 * 512 * 4);
    u16* t1 = wT;    // wT dead after decoder; 5.24MB >= 2.93MB
    u16* t2 = pre1;  // pre1 dead after decoder; 3.21MB >= 2.93MB

    u16* c_a     = conv + 0;
    u16* c_h0    = conv + 3211264;
    u16* c_c0    = conv + 3227648;
    u16* c_attw1 = conv + 3244032;
    u16* c_attb1 = conv + 3506176;
    u16* c_attw2 = conv + 3506432;
    u16* c_attb2 = conv + 3539200;
    u16* c_attw3 = conv + 3539328;
    u16* c_wih   = conv + 3539456;
    u16* c_whh   = conv + 5112320;
    u16* c_bih   = conv + 6160896;
    u16* c_bhh   = conv + 6162944;
    u16* c_emb   = conv + 6164992;
    u16* c_ow1   = conv + 6296064;
    u16* c_ob1   = conv + 6754304;
    u16* c_ow2   = conv + 6754664;
    u16* c_ob2   = conv + 6882832;
    u16* c_ow3   = conv + 6883192;
    u16* c_ob3   = conv + 7066488;

    ConvPtrs cp;
    {
        const int idx[19] = {0, 1, 2, 4, 5, 6, 7, 8, 10, 11, 12, 13, 14, 15, 16, 17, 18, 19, 20};
        for (int i = 0; i < 19; ++i) cp.p[i] = d_in[idx[i]];
    }

    detect_kernel<<<1, 64, 0, stream>>>((const u16*)d_in[4], flg, bars);
    conv_kernel<<<6902, 256, 0, stream>>>(cp, flg, conv);
    prep_kernel<<<2432, 256, 0, stream>>>(c_wih, c_whh, c_attw1, c_attw2, wT, w1hT, w2T);
    embed_kernel<<<1024, 256, 0, stream>>>(y, c_emb, hze);
    gemm_kernel<false, 1><<<dim3(4, 49), 256, 0, stream>>>(
        c_a, 512, c_attw1, 256, c_attb1, pre1, 256, 6272, 256, 512, flg);

    DecArgs g;
    g.h0 = c_h0; g.c0 = c_c0; g.pre1 = pre1; g.w2T = w2T; g.att_b2 = c_attb2;
    g.att_w3 = c_attw3; g.w1hT = w1hT; g.wT = wT; g.bih = c_bih; g.bhh = c_bhh;
    g.a = c_a; g.hze = hze; g.h0b = h0b; g.s_buf = s_buf; g.c_buf = c_buf; g.bars = bars;
    decoder_kernel<<<GRID_, 256, 0, stream>>>(g);

    gemm_kernel<true, 1><<<dim3(6, 32), 256, 0, stream>>>(
        hze, 1280, c_ow1, 358, c_ob1, t1, 358, 4096, 358, 1280, flg);
    gemm_kernel<true, 1><<<dim3(6, 32), 256, 0, stream>>>(
        t1, 358, c_ow2, 358, c_ob2, t2, 358, 4096, 358, 358, flg);
    gemm_kernel<false, 2><<<dim3(8, 32), 256, 0, stream>>>(
        t2, 358, c_ow3, 512, c_ob3, d_out, 512, 4096, 512, 358, flg);
}

// Round 7
// 6604.795 us; speedup vs baseline: 3.9938x; 1.0735x over previous
//
#include <hip/hip_runtime.h>
#include <hip/hip_bf16.h>
#include <cstdint>

#define B_ 32
#define L_ 196
#define D_ 512
#define H_ 512
#define E_ 256
#define T_ 128
#define V_ 512
#define GRID_ 256
#define NBARS 5504
// bars layout (ints): slot(blk)=blk*16 [0..4095]; release(r)=4096+r*16 (16 lines);
// group-arrival(gb)=4352+gb*16; group-release(gb)=4864+gb*16.

using u16 = unsigned short;

__device__ __forceinline__ float bf2f(u16 u) { return __uint_as_float(((unsigned)u) << 16); }
__device__ __forceinline__ u16 f2bf(float f) {
    unsigned u = __float_as_uint(f);
    return (u16)((u + 0x7FFFu + ((u >> 16) & 1u)) >> 16);
}
__device__ __forceinline__ float2 bfp(unsigned u) {
    return make_float2(__uint_as_float(u << 16), __uint_as_float(u & 0xffff0000u));
}
__device__ __forceinline__ float sigm(float x) { return 1.f / (1.f + __expf(-x)); }
__device__ __forceinline__ float tanh_fast(float x) { return 1.f - 2.f / (__expf(2.f * x) + 1.f); }

// --- coherent (cache-bypass) payload access: relaxed agent-scope atomics.
__device__ __forceinline__ float ldcf(const float* p) {
    return __hip_atomic_load((float*)p, __ATOMIC_RELAXED, __HIP_MEMORY_SCOPE_AGENT);
}
__device__ __forceinline__ int ldci(const int* p) {
    return __hip_atomic_load((int*)p, __ATOMIC_RELAXED, __HIP_MEMORY_SCOPE_AGENT);
}
__device__ __forceinline__ unsigned ldc32(const void* p) {
    return __hip_atomic_load((unsigned*)p, __ATOMIC_RELAXED, __HIP_MEMORY_SCOPE_AGENT);
}
__device__ __forceinline__ uint2 ldcu4h(const u16* p) {  // 4 bf16 (8B)
    unsigned long long v = __hip_atomic_load((unsigned long long*)p, __ATOMIC_RELAXED,
                                             __HIP_MEMORY_SCOPE_AGENT);
    union { unsigned long long u; uint2 f; } c; c.u = v; return c.f;
}
__device__ __forceinline__ void stcf(float* p, float v) {
    __hip_atomic_store(p, v, __ATOMIC_RELAXED, __HIP_MEMORY_SCOPE_AGENT);
}
__device__ __forceinline__ void stci(int* p, int v) {
    __hip_atomic_store(p, v, __ATOMIC_RELAXED, __HIP_MEMORY_SCOPE_AGENT);
}
__device__ __forceinline__ void stcu(unsigned* p, unsigned v) {
    __hip_atomic_store(p, v, __ATOMIC_RELAXED, __HIP_MEMORY_SCOPE_AGENT);
}

// ---------------- dtype detect + barrier reset ----------------
__global__ void detect_kernel(const u16* __restrict__ w, int* __restrict__ flg,
                              int* __restrict__ bars) {
    for (int i = threadIdx.x; i < NBARS; i += 64) bars[i] = 0;
    if (threadIdx.x == 0) {
        int cnt = 0;
        for (int i = 0; i < 64; ++i) {
            int e = (w[i] >> 7) & 0xFF;
            cnt += (e >= 100 && e <= 130);
        }
        flg[0] = (cnt >= 56) ? 1 : 0;
    }
}

// ---------------- convert all float tensors to internal bf16 ----------------
struct ConvPtrs { const void* p[19]; };

__global__ __launch_bounds__(256) void conv_kernel(ConvPtrs cp, const int* __restrict__ flg,
                                                   u16* __restrict__ dst) {
    constexpr int NT = 19;
    constexpr unsigned off[NT + 1] = {
        0u, 3211264u, 3227648u, 3244032u, 3506176u, 3506432u, 3539200u, 3539328u,
        3539456u, 5112320u, 6160896u, 6162944u, 6164992u, 6296064u, 6754304u,
        6754664u, 6882832u, 6883192u, 7066488u, 7067000u};
    constexpr unsigned realN[NT] = {
        3211264u, 16384u, 16384u, 262144u, 256u, 32768u, 128u, 128u,
        1572864u, 1048576u, 2048u, 2048u, 131072u, 458240u, 358u,
        128164u, 358u, 183296u, 512u};
    unsigned pos = (blockIdx.x * 256u + threadIdx.x) * 4u;
    if (pos >= off[NT]) return;
    int t = 0;
#pragma unroll
    for (int i = 1; i < NT; ++i) t += (pos >= off[i]);
    unsigned local = pos - off[t];
    int bf = flg[0];
    const void* src = cp.p[t];
    u16* d = dst + off[t];
#pragma unroll
    for (int j = 0; j < 4; ++j) {
        unsigned l = local + j;
        u16 v = 0;
        if (l < realN[t]) v = bf ? ((const u16*)src)[l] : f2bf(((const float*)src)[l]);
        d[l] = v;
    }
}

// ---------------- weight transposes: wT, w1hT, w2T ----------------
__global__ __launch_bounds__(256) void prep_kernel(const u16* __restrict__ w_ih,
                                                   const u16* __restrict__ w_hh,
                                                   const u16* __restrict__ att_w1,
                                                   const u16* __restrict__ att_w2,
                                                   u16* __restrict__ wT,
                                                   u16* __restrict__ w1hT,
                                                   u16* __restrict__ w2T) {
    int c = blockIdx.x, t = threadIdx.x;
    if (c < 2048) {
#pragma unroll
        for (int i = 0; i < 5; ++i) {
            int k = i * 256 + t;
            u16 v = (k < 768) ? w_ih[(size_t)k * 2048 + c] : w_hh[(size_t)(k - 768) * 2048 + c];
            wT[(size_t)c * 1280 + k] = v;
        }
    } else if (c < 2304) {
        int c2 = c - 2048;
#pragma unroll
        for (int i = 0; i < 2; ++i) {
            int k = i * 256 + t;
            w1hT[(size_t)c2 * 512 + k] = att_w1[(size_t)(512 + k) * 256 + c2];
        }
    } else {
        int c3 = c - 2304;
        w2T[c3 * 256 + t] = att_w2[(size_t)t * 128 + c3];
    }
}

// ---------------- embedding (shifted y) -> hze e-part ----------------
__global__ __launch_bounds__(256) void embed_kernel(const int* __restrict__ y,
                                                    const u16* __restrict__ emb,
                                                    u16* __restrict__ hze) {
    int t = threadIdx.x;
    int row0 = blockIdx.x * 4;
    for (int i = 0; i < 4; ++i) {
        int row = row0 + i;
        int b = row >> 7, tt = row & 127;
        int yin = tt ? y[b * T_ + tt - 1] : 0;
        hze[(size_t)row * 1280 + 1024 + t] = emb[yin * E_ + t];
    }
}

// ---------------- generic tiled GEMM: C = act(A @ Bw + bias) ----------------
template <bool TANH, int OMODE>
__global__ __launch_bounds__(256) void gemm_kernel(const u16* __restrict__ A, int lda,
                                                   const u16* __restrict__ Bw, int ldb,
                                                   const u16* __restrict__ bias,
                                                   void* __restrict__ Cv, int ldc,
                                                   int M, int N, int K,
                                                   const int* __restrict__ flg) {
    __shared__ float As[16][132];
    __shared__ float Bs[16][68];
    int t = threadIdx.x;
    int n0 = blockIdx.x * 64;
    int m0 = blockIdx.y * 128;
    int tx = t & 15, ty = t >> 4;
    float acc[8][4];
#pragma unroll
    for (int i = 0; i < 8; ++i)
#pragma unroll
        for (int j = 0; j < 4; ++j) acc[i][j] = 0.f;

    int ar = t >> 1, akb = (t & 1) * 8;
    int bn = t & 63, bkg = t >> 6;

    for (int k0 = 0; k0 < K; k0 += 16) {
        const u16* Ap = A + (size_t)(m0 + ar) * lda + k0 + akb;
        if (k0 + 16 <= K) {
#pragma unroll
            for (int i = 0; i < 8; ++i) As[akb + i][ar] = bf2f(Ap[i]);
        } else {
#pragma unroll
            for (int i = 0; i < 8; ++i) As[akb + i][ar] = (k0 + akb + i < K) ? bf2f(Ap[i]) : 0.f;
        }
#pragma unroll
        for (int i = 0; i < 4; ++i) {
            int kk = bkg * 4 + i;
            int kg = k0 + kk, ng = n0 + bn;
            Bs[kk][bn] = (kg < K && ng < N) ? bf2f(Bw[(size_t)kg * ldb + ng]) : 0.f;
        }
        __syncthreads();
#pragma unroll
        for (int kk = 0; kk < 16; ++kk) {
            float4 aA = *(const float4*)&As[kk][ty * 8];
            float4 aB = *(const float4*)&As[kk][ty * 8 + 4];
            float4 bv = *(const float4*)&Bs[kk][tx * 4];
            float av[8] = {aA.x, aA.y, aA.z, aA.w, aB.x, aB.y, aB.z, aB.w};
            float bb[4] = {bv.x, bv.y, bv.z, bv.w};
#pragma unroll
            for (int i = 0; i < 8; ++i)
#pragma unroll
                for (int j = 0; j < 4; ++j) acc[i][j] += av[i] * bb[j];
        }
        __syncthreads();
    }
    int obf = (OMODE == 2) ? flg[0] : 1;
    float bb[4];
#pragma unroll
    for (int j = 0; j < 4; ++j) {
        int n = n0 + tx * 4 + j;
        bb[j] = (n < N) ? bf2f(bias[n]) : 0.f;
    }
#pragma unroll
    for (int i = 0; i < 8; ++i) {
        int m = m0 + ty * 8 + i;
#pragma unroll
        for (int j = 0; j < 4; ++j) {
            int n = n0 + tx * 4 + j;
            if (n < N) {
                float v = acc[i][j] + bb[j];
                if (TANH) v = tanhf(v);
                if (OMODE == 1 || obf)
                    ((u16*)Cv)[(size_t)m * ldc + n] = f2bf(v);
                else
                    ((float*)Cv)[(size_t)m * ldc + n] = v;
            }
        }
    }
}

// ---------------- persistent decoder ----------------
struct DecArgs {
    const u16 *h0, *c0, *pre1, *w2T, *att_b2, *att_w3, *w1hT, *wT, *bih, *bhh, *a;
    u16 *hze, *h0b;
    float *s_buf, *c_buf;
    int* bars;
};

struct SA { float x1s[28][264]; float part[28][36]; };
struct SB { float red[256]; float alpha[200]; float zred[64][5]; };
union SU { SA a; SB b; float hs[512]; };

// Grid barrier: store-slot + checker-block. Leaders store epoch to private lines
// (no contention); block 0 polls all 256 slots with one vector round, then
// broadcasts release to 16 replicated lines (16 pollers each). All relaxed;
// payload safety: __syncthreads drains vmcnt before the slot store.
__device__ __forceinline__ void gridbar(int* bars, int blk, int t, int epoch) {
    __syncthreads();
    if (t == 0) stci(&bars[blk << 4], epoch);
    if (blk == 0) {
        for (;;) {
            int v = ldci(&bars[t << 4]);
            if (__syncthreads_count(v < epoch) == 0) break;
            __builtin_amdgcn_s_sleep(4);
        }
        if (t < 16) stci(&bars[4096 + (t << 4)], epoch);
        __syncthreads();
    } else {
        if (t == 0) {
            while (ldci(&bars[4096 + ((blk & 15) << 4)]) < epoch)
                __builtin_amdgcn_s_sleep(8);
        }
        __syncthreads();
    }
}

__global__ __launch_bounds__(256) void decoder_kernel(DecArgs g) {
    int blk = blockIdx.x, t = threadIdx.x;
    __shared__ SU su;
    __shared__ u16 wlds[8][1288];
    __shared__ unsigned csta[32][68];
    __shared__ float accs[32][9];
    __shared__ float hsh[32][2];
    __shared__ float w3s[128], b2s[128];
    int gep = 0, pep = 0;

    // XCD-aware mapping: blocks with equal blk%8 share an XCD; a batch's 8
    // blocks stay on one XCD (group barrier + `a` reads are L2-local).
    int ab = (blk & 7) * 4 + (blk >> 6);
    int ach = (blk >> 3) & 7;

    int d0 = blk * 2;
#pragma unroll
    for (int i = 0; i < 5; ++i) {
        int v = i * 256 + t;           // 1280 vec8 total
        int cidx = v / 160, k8 = v % 160;
        int col = (cidx >> 1) * 512 + d0 + (cidx & 1);
        *(uint4*)&wlds[cidx][k8 * 8] = *(const uint4*)(g.wT + (size_t)col * 1280 + k8 * 8);
    }
    if (t < 128) {
        w3s[t] = bf2f(g.att_w3[t]);
        b2s[t] = bf2f(g.att_b2[t]);
    }
    float bsum[4];
    {
        int bj = t & 1;
#pragma unroll
        for (int q = 0; q < 4; ++q) {
            int col = q * 512 + d0 + bj;
            bsum[q] = bf2f(g.bih[col]) + bf2f(g.bhh[col]);
        }
    }
    if (blk < 32) {
        for (int i = t; i < 512; i += 256)
            stcf(&g.c_buf[blk * 512 + i], bf2f(g.c0[blk * 512 + i]));
        unsigned pk = (unsigned)g.h0[blk * 512 + 2 * t] |
                      ((unsigned)g.h0[blk * 512 + 2 * t + 1] << 16);
        stcu((unsigned*)(g.h0b + blk * 512 + 2 * t), pk);
    }
    gridbar(g.bars, blk, t, ++gep);

    int anrows = (ach == 7) ? 21 : 25;
    int arow0 = ab * 196 + ach * 25;
    int cb = t >> 3, cc = t & 7;

    for (int step = 0; step < T_; ++step) {
        float acc8[8];
#pragma unroll
        for (int i = 0; i < 8; ++i) acc8[i] = 0.f;
        // gate-GEMM chunk engine (shared acc8); ck 0-3: z, 4-5: e, 6-9: h(t-1)
        auto cchunks = [&](int ck0, int ck1) {
            uint2 raw[4];
            auto issueo = [&](int ck) {
#pragma unroll
                for (int i = 0; i < 4; ++i) {
                    int v = i * 256 + t, bb = v >> 5, kk = (v & 31) * 4;
                    if (ck < 4) {
                        raw[i] = ldcu4h(g.hze + (size_t)(bb * T_ + step) * 1280 + 512 +
                                        ck * 128 + kk);
                    } else if (ck < 6) {
                        raw[i] = *(const uint2*)(g.hze + (size_t)(bb * T_ + step) * 1280 + 1024 +
                                                 (ck - 4) * 128 + kk);  // e: static, cached
                    } else {
                        const u16* hp = step ? (g.hze + (size_t)(bb * T_ + step - 1) * 1280)
                                             : (g.h0b + bb * 512);
                        raw[i] = ldcu4h(hp + (ck - 6) * 128 + kk);
                    }
                }
            };
            issueo(ck0);
            for (int ck = ck0; ck < ck1; ++ck) {
                __syncthreads();
#pragma unroll
                for (int i = 0; i < 4; ++i) {
                    int v = i * 256 + t, bb = v >> 5, k2 = (v & 31) * 2;
                    *(uint2*)&csta[bb][k2] = raw[i];
                }
                if (ck + 1 < ck1) issueo(ck + 1);
                __syncthreads();
                const u16* wrow = &wlds[cc][ck * 128];
                const unsigned* irow = &csta[cb][0];
#pragma unroll
                for (int k8 = 0; k8 < 16; ++k8) {
                    uint4 iv = *(const uint4*)(irow + k8 * 4);
                    uint4 wv = *(const uint4*)(wrow + k8 * 8);
                    float2 i0 = bfp(iv.x), i1 = bfp(iv.y), i2 = bfp(iv.z), i3 = bfp(iv.w);
                    float2 w0 = bfp(wv.x), w1 = bfp(wv.y), w2 = bfp(wv.z), w3 = bfp(wv.w);
                    acc8[0] += i0.x * w0.x; acc8[1] += i0.y * w0.y;
                    acc8[2] += i1.x * w1.x; acc8[3] += i1.y * w1.y;
                    acc8[4] += i2.x * w2.x; acc8[5] += i2.y * w2.y;
                    acc8[6] += i3.x * w3.x; acc8[7] += i3.y * w3.y;
                }
            }
        };

        // ================= stage A: hterm + attention MLP scores =================
        const u16* hsrcA = step ? (g.hze + (size_t)(ab * T_ + step - 1) * 1280)
                                : (g.h0b + ab * 512);
        {
            float2 hp = bfp(ldc32(hsrcA + 2 * t));
            su.hs[2 * t] = hp.x;
            su.hs[2 * t + 1] = hp.y;
        }
        __syncthreads();
        float htv;
        {
            float ha[8] = {0.f, 0.f, 0.f, 0.f, 0.f, 0.f, 0.f, 0.f};
            const u16* wp = g.w1hT + (size_t)t * 512;
#pragma unroll 4
            for (int k = 0; k < 512; k += 8) {
                uint4 wv = *(const uint4*)(wp + k);
                float4 hA = *(const float4*)&su.hs[k];
                float4 hB = *(const float4*)&su.hs[k + 4];
                float2 w01 = bfp(wv.x), w23 = bfp(wv.y), w45 = bfp(wv.z), w67 = bfp(wv.w);
                ha[0] += hA.x * w01.x; ha[1] += hA.y * w01.y;
                ha[2] += hA.z * w23.x; ha[3] += hA.w * w23.y;
                ha[4] += hB.x * w45.x; ha[5] += hB.y * w45.y;
                ha[6] += hB.z * w67.x; ha[7] += hB.w * w67.y;
            }
            htv = ((ha[0] + ha[1]) + (ha[2] + ha[3])) + ((ha[4] + ha[5]) + (ha[6] + ha[7]));
        }
        __syncthreads();  // hs dead; reuse region as x1s
        for (int r = 0; r < 28; ++r) {
            float v = 0.f;
            if (r < anrows) v = tanh_fast(bf2f(g.pre1[(size_t)(arow0 + r) * 256 + t]) + htv);
            su.a.x1s[r][t] = v;
        }
        __syncthreads();
        if (t < 224) {
            int r0 = (t >> 5) * 4, c0v = (t & 31) * 4;
            float acc[4][4];
#pragma unroll
            for (int i = 0; i < 4; ++i)
#pragma unroll
                for (int j = 0; j < 4; ++j) acc[i][j] = 0.f;
            for (int k8 = 0; k8 < 256; k8 += 8) {
                uint4 wv[4];
#pragma unroll
                for (int j = 0; j < 4; ++j)
                    wv[j] = *(const uint4*)(g.w2T + (size_t)(c0v + j) * 256 + k8);
                float4 xa[4], xb[4];
#pragma unroll
                for (int i = 0; i < 4; ++i) {
                    xa[i] = *(const float4*)&su.a.x1s[r0 + i][k8];
                    xb[i] = *(const float4*)&su.a.x1s[r0 + i][k8 + 4];
                }
#pragma unroll
                for (int j = 0; j < 4; ++j) {
                    float2 w0 = bfp(wv[j].x), w1 = bfp(wv[j].y);
                    float2 w2 = bfp(wv[j].z), w3 = bfp(wv[j].w);
#pragma unroll
                    for (int i = 0; i < 4; ++i)
                        acc[i][j] += xa[i].x * w0.x + xa[i].y * w0.y + xa[i].z * w1.x +
                                     xa[i].w * w1.y + xb[i].x * w2.x + xb[i].y * w2.y +
                                     xb[i].z * w3.x + xb[i].w * w3.y;
                }
            }
#pragma unroll
            for (int i = 0; i < 4; ++i) {
                float p = 0.f;
#pragma unroll
                for (int j = 0; j < 4; ++j)
                    p += tanh_fast(acc[i][j] + b2s[c0v + j]) * w3s[c0v + j];
                su.a.part[r0 + i][t & 31] = p;
            }
        }
        __syncthreads();
        if (t < anrows) {
            float s = 0.f;
#pragma unroll
            for (int cg = 0; cg < 32; ++cg) s += su.a.part[t][cg];
            stcf(&g.s_buf[arow0 + t], s);  // att_b3 omitted: softmax-invariant
        }
        // --- group-barrier post (8 blocks of batch ab) ---
        __syncthreads();
        ++pep;
        if (t == 0) {
            int old = __hip_atomic_fetch_add(&g.bars[4352 + (ab << 4)], 1, __ATOMIC_RELAXED,
                                             __HIP_MEMORY_SCOPE_AGENT);
            if (old == pep * 8 - 1) stci(&g.bars[4864 + (ab << 4)], pep);
        }
        // --- hidden work: gate-GEMM e/h chunks (only needs step-1 state) ---
        cchunks(4, 10);
        // --- group-barrier wait ---
        if (t == 0) {
            while (ldci(&g.bars[4864 + (ab << 4)]) < pep) __builtin_amdgcn_s_sleep(4);
        }
        __syncthreads();
        // ================= stage B: softmax + context z =================
        {
            float v = (t < L_) ? ldcf(&g.s_buf[ab * L_ + t]) : -1e30f;
            su.b.red[t] = v;
            __syncthreads();
            for (int off = 128; off > 0; off >>= 1) {
                if (t < off) su.b.red[t] = fmaxf(su.b.red[t], su.b.red[t + off]);
                __syncthreads();
            }
            float mx = su.b.red[0];
            __syncthreads();
            float e = (t < L_) ? __expf(v - mx) : 0.f;
            su.b.red[t] = e;
            __syncthreads();
            for (int off = 128; off > 0; off >>= 1) {
                if (t < off) su.b.red[t] += su.b.red[t + off];
                __syncthreads();
            }
            float inv = 1.f / su.b.red[0];
            __syncthreads();
            if (t < L_) su.b.alpha[t] = e * inv;
            __syncthreads();
            int dl = t >> 2, lq = t & 3;
            const u16* ap = g.a + (size_t)ab * L_ * 512 + ach * 64 + dl;
            float zp = 0.f;
            int l0 = lq * 49;
            for (int l = l0; l < l0 + 49; ++l) zp += su.b.alpha[l] * bf2f(ap[(size_t)l * 512]);
            su.b.zred[dl][lq] = zp;
            __syncthreads();
            if (t < 32) {
                float z0 = su.b.zred[2 * t][0] + su.b.zred[2 * t][1] +
                           su.b.zred[2 * t][2] + su.b.zred[2 * t][3];
                float z1 = su.b.zred[2 * t + 1][0] + su.b.zred[2 * t + 1][1] +
                           su.b.zred[2 * t + 1][2] + su.b.zred[2 * t + 1][3];
                unsigned pk = (unsigned)f2bf(z0) | ((unsigned)f2bf(z1) << 16);
                stcu((unsigned*)(g.hze + (size_t)(ab * T_ + step) * 1280 + 512 + ach * 64 + 2 * t),
                     pk);
            }
        }
        gridbar(g.bars, blk, t, ++gep);  // z visible to all
        // ================= stage C: z chunks + state update =================
        cchunks(0, 4);
        {
            float acc = ((acc8[0] + acc8[1]) + (acc8[2] + acc8[3])) +
                        ((acc8[4] + acc8[5]) + (acc8[6] + acc8[7]));
            __syncthreads();
            accs[cb][cc] = acc;
            __syncthreads();
            if (t < 64) {
                int bb = t >> 1, j = t & 1;
                int d = d0 + j;
                float gg[4];
#pragma unroll
                for (int q = 0; q < 4; ++q) gg[q] = accs[bb][q * 2 + j] + bsum[q];
                float gi = sigm(gg[0]), gf = sigm(gg[1]);
                float gn = tanh_fast(gg[2]), go = sigm(gg[3]);
                float cn = gf * g.c_buf[bb * 512 + d] + gi * gn;
                g.c_buf[bb * 512 + d] = cn;   // block-private after init
                hsh[bb][j] = go * tanh_fast(cn);
            }
            __syncthreads();
            if (t < 64 && !(t & 1)) {
                int bb = t >> 1;
                float2 hp = *(float2*)&hsh[bb][0];
                unsigned pk = (unsigned)f2bf(hp.x) | ((unsigned)f2bf(hp.y) << 16);
                stcu((unsigned*)(g.hze + (size_t)(bb * T_ + step) * 1280 + d0), pk);
            }
        }
        gridbar(g.bars, blk, t, ++gep);  // h visible to all
    }
}

extern "C" void kernel_launch(void* const* d_in, const int* in_sizes, int n_in,
                              void* d_out, int out_size, void* d_ws, size_t ws_size,
                              hipStream_t stream) {
    (void)in_sizes; (void)n_in; (void)out_size; (void)ws_size;
    const int* y = (const int*)d_in[3];

    char* base = (char*)d_ws;
    size_t off = 0;
    auto alloc = [&](size_t bytes) {
        void* p = base + off;
        off = (off + bytes + 63) & ~(size_t)63;
        return p;
    };
    // Total footprint ~33.6 MB — must stay <= 34.34 MB (round-2 proven bound).
    int* flg   = (int*)alloc(64);
    int* bars  = (int*)alloc(NBARS * 4);
    u16* conv  = (u16*)alloc((size_t)7067000 * 2);
    u16* pre1  = (u16*)alloc((size_t)6272 * 256 * 2);   // t2 aliases after decoder
    u16* hze   = (u16*)alloc((size_t)4096 * 1280 * 2);
    u16* wT    = (u16*)alloc((size_t)2048 * 1280 * 2);  // t1 aliases after decoder
    u16* w1hT  = (u16*)alloc((size_t)256 * 512 * 2);
    u16* w2T   = (u16*)alloc((size_t)128 * 256 * 2);
    u16* h0b   = (u16*)alloc((size_t)32 * 512 * 2);
    float* s_buf = (float*)alloc(32 * 196 * 4);
    float* c_buf = (float*)alloc(32 * 512 * 4);
    u16* t1 = wT;    // wT dead after decoder; 5.24MB >= 2.93MB
    u16* t2 = pre1;  // pre1 dead after decoder; 3.21MB >= 2.93MB

    u16* c_a     = conv + 0;
    u16* c_h0    = conv + 3211264;
    u16* c_c0    = conv + 3227648;
    u16* c_attw1 = conv + 3244032;
    u16* c_attb1 = conv + 3506176;
    u16* c_attw2 = conv + 3506432;
    u16* c_attb2 = conv + 3539200;
    u16* c_attw3 = conv + 3539328;
    u16* c_wih   = conv + 3539456;
    u16* c_whh   = conv + 5112320;
    u16* c_bih   = conv + 6160896;
    u16* c_bhh   = conv + 6162944;
    u16* c_emb   = conv + 6164992;
    u16* c_ow1   = conv + 6296064;
    u16* c_ob1   = conv + 6754304;
    u16* c_ow2   = conv + 6754664;
    u16* c_ob2   = conv + 6882832;
    u16* c_ow3   = conv + 6883192;
    u16* c_ob3   = conv + 7066488;

    ConvPtrs cp;
    {
        const int idx[19] = {0, 1, 2, 4, 5, 6, 7, 8, 10, 11, 12, 13, 14, 15, 16, 17, 18, 19, 20};
        for (int i = 0; i < 19; ++i) cp.p[i] = d_in[idx[i]];
    }

    detect_kernel<<<1, 64, 0, stream>>>((const u16*)d_in[4], flg, bars);
    conv_kernel<<<6902, 256, 0, stream>>>(cp, flg, conv);
    prep_kernel<<<2432, 256, 0, stream>>>(c_wih, c_whh, c_attw1, c_attw2, wT, w1hT, w2T);
    embed_kernel<<<1024, 256, 0, stream>>>(y, c_emb, hze);
    gemm_kernel<false, 1><<<dim3(4, 49), 256, 0, stream>>>(
        c_a, 512, c_attw1, 256, c_attb1, pre1, 256, 6272, 256, 512, flg);

    DecArgs g;
    g.h0 = c_h0; g.c0 = c_c0; g.pre1 = pre1; g.w2T = w2T; g.att_b2 = c_attb2;
    g.att_w3 = c_attw3; g.w1hT = w1hT; g.wT = wT; g.bih = c_bih; g.bhh = c_bhh;
    g.a = c_a; g.hze = hze; g.h0b = h0b; g.s_buf = s_buf; g.c_buf = c_buf; g.bars = bars;
    decoder_kernel<<<GRID_, 256, 0, stream>>>(g);

    gemm_kernel<true, 1><<<dim3(6, 32), 256, 0, stream>>>(
        hze, 1280, c_ow1, 358, c_ob1, t1, 358, 4096, 358, 1280, flg);
    gemm_kernel<true, 1><<<dim3(6, 32), 256, 0, stream>>>(
        t1, 358, c_ow2, 358, c_ob2, t2, 358, 4096, 358, 358, flg);
    gemm_kernel<false, 2><<<dim3(8, 32), 256, 0, stream>>>(
        t2, 358, c_ow3, 512, c_ob3, d_out, 512, 4096, 512, 358, flg);
}